// Round 1
// baseline (230.334 us; speedup 1.0000x reference)
//
#include <hip/hip_runtime.h>
#include <stdint.h>
#include <stddef.h>

#define NTOK   2048
#define NHEAD  16
#define DHEAD  64
#define DMODEL 1024
#define NROWS  4096      // B * NTOK
#define NQKV   3072
#define RMS_EPS 1.1920928955078125e-07f

typedef short bf16x8 __attribute__((ext_vector_type(8)));
typedef float f32x4  __attribute__((ext_vector_type(4)));
typedef unsigned short u16x4 __attribute__((ext_vector_type(4)));

__device__ __forceinline__ unsigned short f2b(float f) {
  unsigned u = __builtin_bit_cast(unsigned, f);
  return (unsigned short)((u + 0x7fffu + ((u >> 16) & 1u)) >> 16);  // RNE
}

__device__ __forceinline__ void gl16(const void* g, void* l) {
  __builtin_amdgcn_global_load_lds((__attribute__((address_space(1))) void*)g,
                                   (__attribute__((address_space(3))) void*)l,
                                   16, 0, 0);
}

// ---------------- RMSNorm: x fp32 [4096][1024] -> xn bf16 ----------------
__global__ __launch_bounds__(256) void k_rmsnorm(const float* __restrict__ x,
                                                 const float* __restrict__ w,
                                                 unsigned short* __restrict__ xn) {
  int row = blockIdx.x;
  int t = threadIdx.x;
  float4 v = ((const float4*)(x + (size_t)row * DMODEL))[t];
  float ss = v.x * v.x + v.y * v.y + v.z * v.z + v.w * v.w;
#pragma unroll
  for (int m = 1; m < 64; m <<= 1) ss += __shfl_xor(ss, m, 64);
  __shared__ float red[4];
  if ((t & 63) == 0) red[t >> 6] = ss;
  __syncthreads();
  float tot = (red[0] + red[1]) + (red[2] + red[3]);
  float rs = rsqrtf(tot * (1.0f / DMODEL) + RMS_EPS);
  float4 wv = ((const float4*)w)[t];
  u16x4 o;
  o.x = f2b(v.x * rs * wv.x);
  o.y = f2b(v.y * rs * wv.y);
  o.z = f2b(v.z * rs * wv.z);
  o.w = f2b(v.w * rs * wv.w);
  *(u16x4*)(xn + (size_t)row * DMODEL + t * 4) = o;
}

// ------------- transpose+convert: W fp32 [K][Nw] -> Wt bf16 [Nw][K] -------------
__global__ __launch_bounds__(256) void k_transpose_bf16(const float* __restrict__ W,
                                                        unsigned short* __restrict__ Wt,
                                                        int K, int Nw) {
  __shared__ float tile[64][65];
  int bk = blockIdx.x * 64;
  int bn = blockIdx.y * 64;
  int t = threadIdx.x;
  int tr = t >> 4;
  int tc = (t & 15) * 4;
#pragma unroll
  for (int rr = 0; rr < 64; rr += 16) {
    float4 v = *(const float4*)&W[(size_t)(bk + tr + rr) * Nw + bn + tc];
    tile[tr + rr][tc + 0] = v.x;
    tile[tr + rr][tc + 1] = v.y;
    tile[tr + rr][tc + 2] = v.z;
    tile[tr + rr][tc + 3] = v.w;
  }
  __syncthreads();
#pragma unroll
  for (int rr = 0; rr < 64; rr += 16) {
    int n = bn + tr + rr;
    u16x4 o;
    o.x = f2b(tile[tc + 0][tr + rr]);
    o.y = f2b(tile[tc + 1][tr + rr]);
    o.z = f2b(tile[tc + 2][tr + rr]);
    o.w = f2b(tile[tc + 3][tr + rr]);
    *(u16x4*)&Wt[(size_t)n * K + bk + tc] = o;
  }
}

// ---------------- QKV GEMM (m97-style 128x128, BK=32) + fused RoPE ----------------
// A = xn [4096][1024] bf16 ; Bt = w_qkv^T [3072][1024] bf16
__global__ __launch_bounds__(256) void k_qkv_gemm(
    const unsigned short* __restrict__ A, const unsigned short* __restrict__ Bt,
    const float* __restrict__ sin_t, const float* __restrict__ cos_t,
    unsigned short* __restrict__ Qh, unsigned short* __restrict__ Kh,
    unsigned short* __restrict__ Vh) {
  __shared__ unsigned short As[128 * 32];
  __shared__ unsigned short Bs[128 * 32];
  int bm = blockIdx.x, bn = blockIdx.y;
  int t = threadIdx.x;
  int l = t & 63, w = t >> 6;
  int wr = w >> 1, wc = w & 1;
  int lr = l & 15, lg = l >> 4;
  f32x4 acc[4][4] = {};

  int srow = t >> 2;           // staging row 0..63
  int scho = (t & 3) * 8;      // element offset within 32-wide row
  const unsigned short* Ag = A + (size_t)(bm * 128 + srow) * DMODEL + scho;
  const unsigned short* Bg = Bt + (size_t)(bn * 128 + srow) * DMODEL + scho;
  unsigned short* lA0 = &As[t * 8];
  unsigned short* lA1 = &As[(t + 256) * 8];
  unsigned short* lB0 = &Bs[t * 8];
  unsigned short* lB1 = &Bs[(t + 256) * 8];

  for (int k0 = 0; k0 < DMODEL; k0 += 32) {
    gl16(Ag + k0, lA0);
    gl16(Ag + k0 + 64 * DMODEL, lA1);
    gl16(Bg + k0, lB0);
    gl16(Bg + k0 + 64 * DMODEL, lB1);
    __syncthreads();
    bf16x8 af[4], bfr[4];
#pragma unroll
    for (int i = 0; i < 4; i++)
      af[i] = *(const bf16x8*)&As[(wr * 64 + i * 16 + lr) * 32 + lg * 8];
#pragma unroll
    for (int j = 0; j < 4; j++)
      bfr[j] = *(const bf16x8*)&Bs[(wc * 64 + j * 16 + lr) * 32 + lg * 8];
#pragma unroll
    for (int i = 0; i < 4; i++)
#pragma unroll
      for (int j = 0; j < 4; j++)
        acc[i][j] = __builtin_amdgcn_mfma_f32_16x16x32_bf16(af[i], bfr[j], acc[i][j], 0, 0, 0);
    __syncthreads();
  }

  // epilogue: cols of this wave = one head of q, k, or v
  int nc0 = bn * 128 + wc * 64;
  int which = nc0 >> 10;              // 0=q 1=k 2=v
  int h = (nc0 & 1023) >> 6;
#pragma unroll
  for (int i = 0; i < 4; i++) {
#pragma unroll
    for (int r = 0; r < 4; r++) {
      int m = bm * 128 + wr * 64 + i * 16 + lg * 4 + r;
      int b = m >> 11;
      int n = m & (NTOK - 1);
      size_t obase = ((size_t)(b * NHEAD + h) * NTOK + n) * DHEAD;
      if (which == 2) {
#pragma unroll
        for (int j = 0; j < 4; j++) Vh[obase + j * 16 + lr] = f2b(acc[i][j][r]);
      } else {
        unsigned short* dst = which ? Kh : Qh;
        float qs = which ? 1.0f : 0.125f;   // fold attn scale into Q
#pragma unroll
        for (int j = 0; j < 2; j++) {
          int d = j * 16 + lr;
          float t1 = acc[i][j][r];
          float t2 = acc[i][j + 2][r];
          float c1 = cos_t[n * DHEAD + d],      s1 = sin_t[n * DHEAD + d];
          float c2 = cos_t[n * DHEAD + d + 32], s2 = sin_t[n * DHEAD + d + 32];
          dst[obase + d]      = f2b((t1 * c1 - t2 * s1) * qs);
          dst[obase + d + 32] = f2b((t2 * c2 + t1 * s2) * qs);
        }
      }
    }
  }
}

// ---------------- flash attention (causal), 4 waves x 16 q-rows, KV tile 64 ----------------
__global__ __launch_bounds__(256) void k_attn(
    const unsigned short* __restrict__ Qh, const unsigned short* __restrict__ Kh,
    const unsigned short* __restrict__ Vh, unsigned short* __restrict__ AO) {
  int qt = blockIdx.x;      // q tile (64 rows)
  int bh = blockIdx.y;      // batch*head
  int t = threadIdx.x;
  int l = t & 63, w = t >> 6;
  int lr = l & 15, lg = l >> 4;
  __shared__ unsigned short Ks[64 * 64];    // [kv][d], XOR-swizzled rows
  __shared__ unsigned short Vt[64 * 64];    // [d][kv], XOR-swizzled rows
  __shared__ unsigned short Ps[4][16 * 64]; // per-wave P, XOR-swizzled rows

  const unsigned short* Qb = Qh + (size_t)bh * NTOK * DHEAD;
  const unsigned short* Kb = Kh + (size_t)bh * NTOK * DHEAD;
  const unsigned short* Vb = Vh + (size_t)bh * NTOK * DHEAD;

  int qrow = qt * 64 + w * 16 + lr;
  bf16x8 aq0 = *(const bf16x8*)&Qb[(size_t)qrow * DHEAD + lg * 8];
  bf16x8 aq1 = *(const bf16x8*)&Qb[(size_t)qrow * DHEAD + 32 + lg * 8];

  f32x4 accO[4] = {};
  float mrow[4] = {-1e38f, -1e38f, -1e38f, -1e38f};
  float lsum[4] = {0.f, 0.f, 0.f, 0.f};

  int srow = t >> 3;   // 0..31 (staging kv row, +32 for second chunk)
  int spc = t & 7;     // 16B chunk within 128B row

  for (int kt = 0; kt <= qt; ++kt) {
    int kv0 = kt * 64;
    // --- K stage: async DMA, source pre-swizzled so swizzled-read works (rule #21)
    gl16(Kb + (size_t)(kv0 + srow) * DHEAD + (spc ^ (srow & 7)) * 8, &Ks[t * 8]);
    gl16(Kb + (size_t)(kv0 + srow + 32) * DHEAD + (spc ^ ((srow + 32) & 7)) * 8,
         &Ks[(t + 256) * 8]);
    // --- V stage: reg transpose into swizzled [d][kv]
    {
      bf16x8 v0 = *(const bf16x8*)&Vb[(size_t)(kv0 + srow) * DHEAD + spc * 8];
      bf16x8 v1 = *(const bf16x8*)&Vb[(size_t)(kv0 + srow + 32) * DHEAD + spc * 8];
#pragma unroll
      for (int j = 0; j < 8; j++) {
        int d = spc * 8 + j;
        int sw = ((d & 7) ^ ((d >> 3) & 7)) << 4;
        *(unsigned short*)((char*)Vt + d * 128 + ((srow * 2) ^ sw)) = (unsigned short)v0[j];
        *(unsigned short*)((char*)Vt + d * 128 + (((srow + 32) * 2) ^ sw)) = (unsigned short)v1[j];
      }
    }
    __syncthreads();
    // --- S = Q K^T  (Q pre-scaled by 1/8)
    f32x4 s[4];
#pragma unroll
    for (int nf = 0; nf < 4; nf++) {
      int krow = nf * 16 + lr;
      const char* kbase = (const char*)Ks + krow * 128;
      bf16x8 bk0 = *(const bf16x8*)(kbase + ((lg * 16) ^ ((krow & 7) << 4)));
      bf16x8 bk1 = *(const bf16x8*)(kbase + ((lg * 16 + 64) ^ ((krow & 7) << 4)));
      f32x4 z = {};
      z = __builtin_amdgcn_mfma_f32_16x16x32_bf16(aq0, bk0, z, 0, 0, 0);
      s[nf] = __builtin_amdgcn_mfma_f32_16x16x32_bf16(aq1, bk1, z, 0, 0, 0);
    }
    // --- causal mask (diagonal tile only)
    if (kt == qt) {
#pragma unroll
      for (int nf = 0; nf < 4; nf++) {
        int kvc = kv0 + nf * 16 + lr;
#pragma unroll
        for (int r = 0; r < 4; r++) {
          int qr = qt * 64 + w * 16 + lg * 4 + r;
          if (kvc > qr) s[nf][r] = -1e38f;
        }
      }
    }
    // --- online softmax (rows live in 16-lane groups)
#pragma unroll
    for (int r = 0; r < 4; r++) {
      float mx = fmaxf(fmaxf(s[0][r], s[1][r]), fmaxf(s[2][r], s[3][r]));
      mx = fmaxf(mx, __shfl_xor(mx, 1, 64));
      mx = fmaxf(mx, __shfl_xor(mx, 2, 64));
      mx = fmaxf(mx, __shfl_xor(mx, 4, 64));
      mx = fmaxf(mx, __shfl_xor(mx, 8, 64));
      float mnew = fmaxf(mrow[r], mx);
      float corr = __expf(mrow[r] - mnew);
      float sum = 0.f;
#pragma unroll
      for (int nf = 0; nf < 4; nf++) {
        float p = __expf(s[nf][r] - mnew);
        s[nf][r] = p;
        sum += p;
      }
      sum += __shfl_xor(sum, 1, 64);
      sum += __shfl_xor(sum, 2, 64);
      sum += __shfl_xor(sum, 4, 64);
      sum += __shfl_xor(sum, 8, 64);
      lsum[r] = lsum[r] * corr + sum;
      mrow[r] = mnew;
#pragma unroll
      for (int df = 0; df < 4; df++) accO[df][r] *= corr;
    }
    // --- P -> LDS (swizzled rows) for PV A-fragments
#pragma unroll
    for (int nf = 0; nf < 4; nf++)
#pragma unroll
      for (int r = 0; r < 4; r++) {
        int prow = lg * 4 + r;
        int pcol = nf * 16 + lr;
        int off = prow * 128 + ((pcol * 2) ^ ((prow & 7) << 4));
        *(unsigned short*)((char*)Ps[w] + off) = f2b(s[nf][r]);
      }
    __syncthreads();
    // --- O += P V
#pragma unroll
    for (int ks = 0; ks < 2; ks++) {
      const char* pbase = (const char*)Ps[w] + lr * 128;
      bf16x8 ap = *(const bf16x8*)(pbase + ((lg * 16 + ks * 64) ^ ((lr & 7) << 4)));
#pragma unroll
      for (int df = 0; df < 4; df++) {
        int col = df * 16 + lr;
        int sw = ((col & 7) ^ ((col >> 3) & 7)) << 4;
        bf16x8 bv = *(const bf16x8*)((const char*)Vt + col * 128 + ((lg * 16 + ks * 64) ^ sw));
        accO[df] = __builtin_amdgcn_mfma_f32_16x16x32_bf16(ap, bv, accO[df], 0, 0, 0);
      }
    }
    __syncthreads();
  }
  // --- normalize and write [b][n][h*64+d] bf16
  int b = bh >> 4, h = bh & 15;
#pragma unroll
  for (int df = 0; df < 4; df++)
#pragma unroll
    for (int r = 0; r < 4; r++) {
      int qr = qt * 64 + w * 16 + lg * 4 + r;
      int d = df * 16 + lr;
      float o = accO[df][r] / lsum[r];
      AO[((size_t)(b * NTOK + qr)) * DMODEL + h * DHEAD + d] = f2b(o);
    }
}

// ---------------- out GEMM: AO bf16 [4096][1024] @ w_o^T + bias -> fp32 ----------------
__global__ __launch_bounds__(256) void k_out_gemm(
    const unsigned short* __restrict__ A, const unsigned short* __restrict__ Bt,
    const float* __restrict__ bias, float* __restrict__ out) {
  __shared__ unsigned short As[128 * 32];
  __shared__ unsigned short Bs[128 * 32];
  int bm = blockIdx.x, bn = blockIdx.y;
  int t = threadIdx.x;
  int l = t & 63, w = t >> 6;
  int wr = w >> 1, wc = w & 1;
  int lr = l & 15, lg = l >> 4;
  f32x4 acc[4][4] = {};

  int srow = t >> 2;
  int scho = (t & 3) * 8;
  const unsigned short* Ag = A + (size_t)(bm * 128 + srow) * DMODEL + scho;
  const unsigned short* Bg = Bt + (size_t)(bn * 128 + srow) * DMODEL + scho;
  unsigned short* lA0 = &As[t * 8];
  unsigned short* lA1 = &As[(t + 256) * 8];
  unsigned short* lB0 = &Bs[t * 8];
  unsigned short* lB1 = &Bs[(t + 256) * 8];

  for (int k0 = 0; k0 < DMODEL; k0 += 32) {
    gl16(Ag + k0, lA0);
    gl16(Ag + k0 + 64 * DMODEL, lA1);
    gl16(Bg + k0, lB0);
    gl16(Bg + k0 + 64 * DMODEL, lB1);
    __syncthreads();
    bf16x8 af[4], bfr[4];
#pragma unroll
    for (int i = 0; i < 4; i++)
      af[i] = *(const bf16x8*)&As[(wr * 64 + i * 16 + lr) * 32 + lg * 8];
#pragma unroll
    for (int j = 0; j < 4; j++)
      bfr[j] = *(const bf16x8*)&Bs[(wc * 64 + j * 16 + lr) * 32 + lg * 8];
#pragma unroll
    for (int i = 0; i < 4; i++)
#pragma unroll
      for (int j = 0; j < 4; j++)
        acc[i][j] = __builtin_amdgcn_mfma_f32_16x16x32_bf16(af[i], bfr[j], acc[i][j], 0, 0, 0);
    __syncthreads();
  }
  int nc0 = bn * 128 + wc * 64;
#pragma unroll
  for (int i = 0; i < 4; i++)
#pragma unroll
    for (int r = 0; r < 4; r++) {
      int m = bm * 128 + wr * 64 + i * 16 + lg * 4 + r;
      float* orow = out + (size_t)m * DMODEL;
#pragma unroll
      for (int j = 0; j < 4; j++) {
        int col = nc0 + j * 16 + lr;
        orow[col] = acc[i][j][r] + bias[col];
      }
    }
}

extern "C" void kernel_launch(void* const* d_in, const int* in_sizes, int n_in,
                              void* d_out, int out_size, void* d_ws, size_t ws_size,
                              hipStream_t stream) {
  const float* x      = (const float*)d_in[0];
  const float* norm_w = (const float*)d_in[1];
  const float* w_qkv  = (const float*)d_in[2];
  const float* w_o    = (const float*)d_in[3];
  const float* b_o    = (const float*)d_in[4];
  const float* sin_t  = (const float*)d_in[5];
  const float* cos_t  = (const float*)d_in[6];
  float* out = (float*)d_out;

  char* ws = (char*)d_ws;
  unsigned short* xn    = (unsigned short*)(ws + (0u << 20));   // 8 MB
  unsigned short* wqkvT = (unsigned short*)(ws + (8u << 20));   // 6 MB
  unsigned short* woT   = (unsigned short*)(ws + (14u << 20));  // 2 MB
  unsigned short* Qh    = (unsigned short*)(ws + (16u << 20));  // 8 MB  [b][h][n][d]
  unsigned short* Kh    = (unsigned short*)(ws + (24u << 20));  // 8 MB
  unsigned short* Vh    = (unsigned short*)(ws + (32u << 20));  // 8 MB
  unsigned short* AO    = (unsigned short*)(ws + (40u << 20));  // 8 MB  [b][n][h*d]

  hipLaunchKernelGGL(k_rmsnorm, dim3(NROWS), dim3(256), 0, stream, x, norm_w, xn);
  hipLaunchKernelGGL(k_transpose_bf16, dim3(16, 48), dim3(256), 0, stream, w_qkv, wqkvT, DMODEL, NQKV);
  hipLaunchKernelGGL(k_transpose_bf16, dim3(16, 16), dim3(256), 0, stream, w_o, woT, DMODEL, DMODEL);
  hipLaunchKernelGGL(k_qkv_gemm, dim3(32, 24), dim3(256), 0, stream, xn, wqkvT, sin_t, cos_t, Qh, Kh, Vh);
  hipLaunchKernelGGL(k_attn, dim3(32, 32), dim3(256), 0, stream, Qh, Kh, Vh, AO);
  hipLaunchKernelGGL(k_out_gemm, dim3(32, 8), dim3(256), 0, stream, AO, woT, b_o, out);
}

// Round 2
// 161.293 us; speedup vs baseline: 1.4280x; 1.4280x over previous
//
#include <hip/hip_runtime.h>
#include <stdint.h>
#include <stddef.h>

#define NTOK   2048
#define NHEAD  16
#define DHEAD  64
#define DMODEL 1024
#define NROWS  4096      // B * NTOK
#define NQKV   3072
#define RMS_EPS 1.1920928955078125e-07f

typedef short bf16x8 __attribute__((ext_vector_type(8)));
typedef float f32x4  __attribute__((ext_vector_type(4)));
typedef unsigned short u16x4 __attribute__((ext_vector_type(4)));

__device__ __forceinline__ unsigned short f2b(float f) {
  unsigned u = __builtin_bit_cast(unsigned, f);
  return (unsigned short)((u + 0x7fffu + ((u >> 16) & 1u)) >> 16);  // RNE
}

__device__ __forceinline__ void gl16(const void* g, void* l) {
  __builtin_amdgcn_global_load_lds((__attribute__((address_space(1))) void*)g,
                                   (__attribute__((address_space(3))) void*)l,
                                   16, 0, 0);
}

// ---------------- RMSNorm: x fp32 [4096][1024] -> xn bf16 ----------------
__global__ __launch_bounds__(256) void k_rmsnorm(const float* __restrict__ x,
                                                 const float* __restrict__ w,
                                                 unsigned short* __restrict__ xn) {
  int row = blockIdx.x;
  int t = threadIdx.x;
  float4 v = ((const float4*)(x + (size_t)row * DMODEL))[t];
  float ss = v.x * v.x + v.y * v.y + v.z * v.z + v.w * v.w;
#pragma unroll
  for (int m = 1; m < 64; m <<= 1) ss += __shfl_xor(ss, m, 64);
  __shared__ float red[4];
  if ((t & 63) == 0) red[t >> 6] = ss;
  __syncthreads();
  float tot = (red[0] + red[1]) + (red[2] + red[3]);
  float rs = rsqrtf(tot * (1.0f / DMODEL) + RMS_EPS);
  float4 wv = ((const float4*)w)[t];
  u16x4 o;
  o.x = f2b(v.x * rs * wv.x);
  o.y = f2b(v.y * rs * wv.y);
  o.z = f2b(v.z * rs * wv.z);
  o.w = f2b(v.w * rs * wv.w);
  *(u16x4*)(xn + (size_t)row * DMODEL + t * 4) = o;
}

// ------------- transpose+convert: W fp32 [K][Nw] -> Wt bf16 [Nw][K] -------------
__global__ __launch_bounds__(256) void k_transpose_bf16(const float* __restrict__ W,
                                                        unsigned short* __restrict__ Wt,
                                                        int K, int Nw) {
  __shared__ float tile[64][65];
  int bk = blockIdx.x * 64;
  int bn = blockIdx.y * 64;
  int t = threadIdx.x;
  int tr = t >> 4;
  int tc = (t & 15) * 4;
#pragma unroll
  for (int rr = 0; rr < 64; rr += 16) {
    float4 v = *(const float4*)&W[(size_t)(bk + tr + rr) * Nw + bn + tc];
    tile[tr + rr][tc + 0] = v.x;
    tile[tr + rr][tc + 1] = v.y;
    tile[tr + rr][tc + 2] = v.z;
    tile[tr + rr][tc + 3] = v.w;
  }
  __syncthreads();
#pragma unroll
  for (int rr = 0; rr < 64; rr += 16) {
    int n = bn + tr + rr;
    u16x4 o;
    o.x = f2b(tile[tc + 0][tr + rr]);
    o.y = f2b(tile[tc + 1][tr + rr]);
    o.z = f2b(tile[tc + 2][tr + rr]);
    o.w = f2b(tile[tc + 3][tr + rr]);
    *(u16x4*)&Wt[(size_t)n * K + bk + tc] = o;
  }
}

// ---------------- QKV GEMM (m97-style 128x128, BK=32) + fused RoPE ----------------
__global__ __launch_bounds__(256) void k_qkv_gemm(
    const unsigned short* __restrict__ A, const unsigned short* __restrict__ Bt,
    const float* __restrict__ sin_t, const float* __restrict__ cos_t,
    unsigned short* __restrict__ Qh, unsigned short* __restrict__ Kh,
    unsigned short* __restrict__ Vh) {
  __shared__ unsigned short As[128 * 32];
  __shared__ unsigned short Bs[128 * 32];
  int bm = blockIdx.x, bn = blockIdx.y;
  int t = threadIdx.x;
  int l = t & 63, w = t >> 6;
  int wr = w >> 1, wc = w & 1;
  int lr = l & 15, lg = l >> 4;
  f32x4 acc[4][4] = {};

  int srow = t >> 2;
  int scho = (t & 3) * 8;
  const unsigned short* Ag = A + (size_t)(bm * 128 + srow) * DMODEL + scho;
  const unsigned short* Bg = Bt + (size_t)(bn * 128 + srow) * DMODEL + scho;
  unsigned short* lA0 = &As[t * 8];
  unsigned short* lA1 = &As[(t + 256) * 8];
  unsigned short* lB0 = &Bs[t * 8];
  unsigned short* lB1 = &Bs[(t + 256) * 8];

  for (int k0 = 0; k0 < DMODEL; k0 += 32) {
    gl16(Ag + k0, lA0);
    gl16(Ag + k0 + 64 * DMODEL, lA1);
    gl16(Bg + k0, lB0);
    gl16(Bg + k0 + 64 * DMODEL, lB1);
    __syncthreads();
    bf16x8 af[4], bfr[4];
#pragma unroll
    for (int i = 0; i < 4; i++)
      af[i] = *(const bf16x8*)&As[(wr * 64 + i * 16 + lr) * 32 + lg * 8];
#pragma unroll
    for (int j = 0; j < 4; j++)
      bfr[j] = *(const bf16x8*)&Bs[(wc * 64 + j * 16 + lr) * 32 + lg * 8];
#pragma unroll
    for (int i = 0; i < 4; i++)
#pragma unroll
      for (int j = 0; j < 4; j++)
        acc[i][j] = __builtin_amdgcn_mfma_f32_16x16x32_bf16(af[i], bfr[j], acc[i][j], 0, 0, 0);
    __syncthreads();
  }

  int nc0 = bn * 128 + wc * 64;
  int which = nc0 >> 10;
  int h = (nc0 & 1023) >> 6;
#pragma unroll
  for (int i = 0; i < 4; i++) {
#pragma unroll
    for (int r = 0; r < 4; r++) {
      int m = bm * 128 + wr * 64 + i * 16 + lg * 4 + r;
      int b = m >> 11;
      int n = m & (NTOK - 1);
      size_t obase = ((size_t)(b * NHEAD + h) * NTOK + n) * DHEAD;
      if (which == 2) {
#pragma unroll
        for (int j = 0; j < 4; j++) Vh[obase + j * 16 + lr] = f2b(acc[i][j][r]);
      } else {
        unsigned short* dst = which ? Kh : Qh;
        float qs = which ? 1.0f : 0.125f;
#pragma unroll
        for (int j = 0; j < 2; j++) {
          int d = j * 16 + lr;
          float t1 = acc[i][j][r];
          float t2 = acc[i][j + 2][r];
          float c1 = cos_t[n * DHEAD + d],      s1 = sin_t[n * DHEAD + d];
          float c2 = cos_t[n * DHEAD + d + 32], s2 = sin_t[n * DHEAD + d + 32];
          dst[obase + d]      = f2b((t1 * c1 - t2 * s1) * qs);
          dst[obase + d + 32] = f2b((t2 * c2 + t1 * s2) * qs);
        }
      }
    }
  }
}

// ---------------- flash attention (causal), dual q-tiles per block ----------------
// block: (bh, i) handles q-tiles qtA=i and qtB=31-i; K/V staged ONCE per kv tile,
// consumed by both groups. Double-buffered staging: issue at iter start, the
// end-of-iter barrier's vmcnt drain finds loads already landed.
__global__ __launch_bounds__(256) void k_attn(
    const unsigned short* __restrict__ Qh, const unsigned short* __restrict__ Kh,
    const unsigned short* __restrict__ Vh, unsigned short* __restrict__ AO) {
  int bh = blockIdx.x;      // 0..31 — x-major so linear%8 = bh%8 -> same-head blocks share an XCD
  int i  = blockIdx.y;      // 0..15
  int qtA = i, qtB = 31 - i;
  int t = threadIdx.x;
  int l = t & 63, w = t >> 6;
  int lr = l & 15, lg = l >> 4;

  __shared__ unsigned short Ks[2][64 * 64];    // [kv][d], XOR-swizzled rows
  __shared__ unsigned short Vt[2][64 * 64];    // [d][kv], XOR-swizzled rows
  __shared__ unsigned short Ps[4][2][16 * 64]; // per-wave, per-group P

  const unsigned short* Qb = Qh + (size_t)bh * NTOK * DHEAD;
  const unsigned short* Kb = Kh + (size_t)bh * NTOK * DHEAD;
  const unsigned short* Vb = Vh + (size_t)bh * NTOK * DHEAD;

  // group 0 = qtB (always active), group 1 = qtA (active while kt<=qtA)
  int qrow0 = qtB * 64 + w * 16 + lr;
  int qrow1 = qtA * 64 + w * 16 + lr;
  bf16x8 aq0[2], aq1[2];
  aq0[0] = *(const bf16x8*)&Qb[(size_t)qrow0 * DHEAD + lg * 8];
  aq1[0] = *(const bf16x8*)&Qb[(size_t)qrow0 * DHEAD + 32 + lg * 8];
  aq0[1] = *(const bf16x8*)&Qb[(size_t)qrow1 * DHEAD + lg * 8];
  aq1[1] = *(const bf16x8*)&Qb[(size_t)qrow1 * DHEAD + 32 + lg * 8];

  f32x4 accO[2][4] = {};
  float mrow[2][4], lsum[2][4];
#pragma unroll
  for (int g = 0; g < 2; g++)
#pragma unroll
    for (int r = 0; r < 4; r++) { mrow[g][r] = -1e38f; lsum[g][r] = 0.f; }

  int srow = t >> 3;           // K staging row 0..31 (+32 second)
  int spc  = t & 7;            // 16B chunk in 128B row
  int vr0  = (t >> 3) * 2;     // V staging row pair (vr0, vr0+1)

  // ---- prologue: stage tile 0 into buf 0
  gl16(Kb + (size_t)srow * DHEAD + (spc ^ (srow & 7)) * 8, &Ks[0][t * 8]);
  gl16(Kb + (size_t)(srow + 32) * DHEAD + (spc ^ ((srow + 32) & 7)) * 8, &Ks[0][(t + 256) * 8]);
  {
    bf16x8 v0 = *(const bf16x8*)&Vb[(size_t)vr0 * DHEAD + spc * 8];
    bf16x8 v1 = *(const bf16x8*)&Vb[(size_t)(vr0 + 1) * DHEAD + spc * 8];
#pragma unroll
    for (int j = 0; j < 8; j++) {
      int d = spc * 8 + j;
      int sw = ((d & 7) ^ ((d >> 3) & 7)) << 4;
      unsigned pk = (unsigned)(unsigned short)v0[j] | ((unsigned)(unsigned short)v1[j] << 16);
      *(unsigned*)((char*)Vt[0] + d * 128 + ((vr0 * 2) ^ sw)) = pk;
    }
  }
  __syncthreads();

  for (int kt = 0; kt <= qtB; ++kt) {
    int cur = kt & 1, nxt = cur ^ 1;
    int kv0 = kt * 64;
    bool notlast = (kt < qtB);
    bool aAct = (kt <= qtA);

    // ---- issue next-tile staging (lands during this tile's compute)
    bf16x8 pv0, pv1;
    if (notlast) {
      int kvn = kv0 + 64;
      gl16(Kb + (size_t)(kvn + srow) * DHEAD + (spc ^ (srow & 7)) * 8, &Ks[nxt][t * 8]);
      gl16(Kb + (size_t)(kvn + srow + 32) * DHEAD + (spc ^ ((srow + 32) & 7)) * 8,
           &Ks[nxt][(t + 256) * 8]);
      pv0 = *(const bf16x8*)&Vb[(size_t)(kvn + vr0) * DHEAD + spc * 8];
      pv1 = *(const bf16x8*)&Vb[(size_t)(kvn + vr0 + 1) * DHEAD + spc * 8];
    }

    // ---- S = Q K^T : K fragments shared by both groups
    f32x4 s[2][4];
#pragma unroll
    for (int nf = 0; nf < 4; nf++) {
      int krow = nf * 16 + lr;
      const char* kbase = (const char*)Ks[cur] + krow * 128;
      bf16x8 bk0 = *(const bf16x8*)(kbase + ((lg * 16) ^ ((krow & 7) << 4)));
      bf16x8 bk1 = *(const bf16x8*)(kbase + ((lg * 16 + 64) ^ ((krow & 7) << 4)));
      f32x4 z0 = {};
      z0 = __builtin_amdgcn_mfma_f32_16x16x32_bf16(aq0[0], bk0, z0, 0, 0, 0);
      s[0][nf] = __builtin_amdgcn_mfma_f32_16x16x32_bf16(aq1[0], bk1, z0, 0, 0, 0);
      if (aAct) {
        f32x4 z1 = {};
        z1 = __builtin_amdgcn_mfma_f32_16x16x32_bf16(aq0[1], bk0, z1, 0, 0, 0);
        s[1][nf] = __builtin_amdgcn_mfma_f32_16x16x32_bf16(aq1[1], bk1, z1, 0, 0, 0);
      }
    }

    // ---- mask + online softmax + P write, per group
#pragma unroll
    for (int g = 0; g < 2; g++) {
      if (g == 0 || aAct) {
        int qtg = g ? qtA : qtB;
        if (kt == qtg) {  // diagonal tile: causal mask
#pragma unroll
          for (int nf = 0; nf < 4; nf++) {
            int kvc = kv0 + nf * 16 + lr;
#pragma unroll
            for (int r = 0; r < 4; r++) {
              int qr = qtg * 64 + w * 16 + lg * 4 + r;
              if (kvc > qr) s[g][nf][r] = -1e38f;
            }
          }
        }
#pragma unroll
        for (int r = 0; r < 4; r++) {
          float mx = fmaxf(fmaxf(s[g][0][r], s[g][1][r]), fmaxf(s[g][2][r], s[g][3][r]));
          mx = fmaxf(mx, __shfl_xor(mx, 1, 64));
          mx = fmaxf(mx, __shfl_xor(mx, 2, 64));
          mx = fmaxf(mx, __shfl_xor(mx, 4, 64));
          mx = fmaxf(mx, __shfl_xor(mx, 8, 64));
          float mnew = fmaxf(mrow[g][r], mx);
          float corr = __expf(mrow[g][r] - mnew);
          float sum = 0.f;
#pragma unroll
          for (int nf = 0; nf < 4; nf++) {
            float p = __expf(s[g][nf][r] - mnew);
            s[g][nf][r] = p;
            sum += p;
          }
          sum += __shfl_xor(sum, 1, 64);
          sum += __shfl_xor(sum, 2, 64);
          sum += __shfl_xor(sum, 4, 64);
          sum += __shfl_xor(sum, 8, 64);
          lsum[g][r] = lsum[g][r] * corr + sum;
          mrow[g][r] = mnew;
#pragma unroll
          for (int df = 0; df < 4; df++) accO[g][df][r] *= corr;
        }
#pragma unroll
        for (int nf = 0; nf < 4; nf++)
#pragma unroll
          for (int r = 0; r < 4; r++) {
            int prow = lg * 4 + r;
            int pcol = nf * 16 + lr;
            int off = prow * 128 + ((pcol * 2) ^ ((prow & 7) << 4));
            *(unsigned short*)((char*)Ps[w][g] + off) = f2b(s[g][nf][r]);
          }
      }
    }

    // ---- O += P V : V fragments shared by both groups
#pragma unroll
    for (int ks = 0; ks < 2; ks++) {
      const char* pb0 = (const char*)Ps[w][0] + lr * 128;
      bf16x8 ap0 = *(const bf16x8*)(pb0 + ((lg * 16 + ks * 64) ^ ((lr & 7) << 4)));
      bf16x8 ap1;
      if (aAct) {
        const char* pb1 = (const char*)Ps[w][1] + lr * 128;
        ap1 = *(const bf16x8*)(pb1 + ((lg * 16 + ks * 64) ^ ((lr & 7) << 4)));
      }
#pragma unroll
      for (int df = 0; df < 4; df++) {
        int col = df * 16 + lr;
        int sw = ((col & 7) ^ ((col >> 3) & 7)) << 4;
        bf16x8 bv = *(const bf16x8*)((const char*)Vt[cur] + col * 128 + ((lg * 16 + ks * 64) ^ sw));
        accO[0][df] = __builtin_amdgcn_mfma_f32_16x16x32_bf16(ap0, bv, accO[0][df], 0, 0, 0);
        if (aAct)
          accO[1][df] = __builtin_amdgcn_mfma_f32_16x16x32_bf16(ap1, bv, accO[1][df], 0, 0, 0);
      }
    }

    // ---- write-late: prefetched V regs -> LDS (vmcnt wait lands here, after PV)
    if (notlast) {
#pragma unroll
      for (int j = 0; j < 8; j++) {
        int d = spc * 8 + j;
        int sw = ((d & 7) ^ ((d >> 3) & 7)) << 4;
        unsigned pk = (unsigned)(unsigned short)pv0[j] | ((unsigned)(unsigned short)pv1[j] << 16);
        *(unsigned*)((char*)Vt[nxt] + d * 128 + ((vr0 * 2) ^ sw)) = pk;
      }
    }
    __syncthreads();
  }

  // ---- epilogue: normalize, write both groups
  int b = bh >> 4, h = bh & 15;
#pragma unroll
  for (int g = 0; g < 2; g++) {
    int qbase = (g ? qtA : qtB) * 64 + w * 16;
#pragma unroll
    for (int df = 0; df < 4; df++)
#pragma unroll
      for (int r = 0; r < 4; r++) {
        int qr = qbase + lg * 4 + r;
        int d = df * 16 + lr;
        float o = accO[g][df][r] / lsum[g][r];
        AO[((size_t)(b * NTOK + qr)) * DMODEL + h * DHEAD + d] = f2b(o);
      }
  }
}

// ---------------- out GEMM: AO bf16 [4096][1024] @ w_o^T + bias -> fp32 ----------------
__global__ __launch_bounds__(256) void k_out_gemm(
    const unsigned short* __restrict__ A, const unsigned short* __restrict__ Bt,
    const float* __restrict__ bias, float* __restrict__ out) {
  __shared__ unsigned short As[128 * 32];
  __shared__ unsigned short Bs[128 * 32];
  int bm = blockIdx.x, bn = blockIdx.y;
  int t = threadIdx.x;
  int l = t & 63, w = t >> 6;
  int wr = w >> 1, wc = w & 1;
  int lr = l & 15, lg = l >> 4;
  f32x4 acc[4][4] = {};

  int srow = t >> 2;
  int scho = (t & 3) * 8;
  const unsigned short* Ag = A + (size_t)(bm * 128 + srow) * DMODEL + scho;
  const unsigned short* Bg = Bt + (size_t)(bn * 128 + srow) * DMODEL + scho;
  unsigned short* lA0 = &As[t * 8];
  unsigned short* lA1 = &As[(t + 256) * 8];
  unsigned short* lB0 = &Bs[t * 8];
  unsigned short* lB1 = &Bs[(t + 256) * 8];

  for (int k0 = 0; k0 < DMODEL; k0 += 32) {
    gl16(Ag + k0, lA0);
    gl16(Ag + k0 + 64 * DMODEL, lA1);
    gl16(Bg + k0, lB0);
    gl16(Bg + k0 + 64 * DMODEL, lB1);
    __syncthreads();
    bf16x8 af[4], bfr[4];
#pragma unroll
    for (int i = 0; i < 4; i++)
      af[i] = *(const bf16x8*)&As[(wr * 64 + i * 16 + lr) * 32 + lg * 8];
#pragma unroll
    for (int j = 0; j < 4; j++)
      bfr[j] = *(const bf16x8*)&Bs[(wc * 64 + j * 16 + lr) * 32 + lg * 8];
#pragma unroll
    for (int i = 0; i < 4; i++)
#pragma unroll
      for (int j = 0; j < 4; j++)
        acc[i][j] = __builtin_amdgcn_mfma_f32_16x16x32_bf16(af[i], bfr[j], acc[i][j], 0, 0, 0);
    __syncthreads();
  }
  int nc0 = bn * 128 + wc * 64;
#pragma unroll
  for (int i = 0; i < 4; i++)
#pragma unroll
    for (int r = 0; r < 4; r++) {
      int m = bm * 128 + wr * 64 + i * 16 + lg * 4 + r;
      float* orow = out + (size_t)m * DMODEL;
#pragma unroll
      for (int j = 0; j < 4; j++) {
        int col = nc0 + j * 16 + lr;
        orow[col] = acc[i][j][r] + bias[col];
      }
    }
}

extern "C" void kernel_launch(void* const* d_in, const int* in_sizes, int n_in,
                              void* d_out, int out_size, void* d_ws, size_t ws_size,
                              hipStream_t stream) {
  const float* x      = (const float*)d_in[0];
  const float* norm_w = (const float*)d_in[1];
  const float* w_qkv  = (const float*)d_in[2];
  const float* w_o    = (const float*)d_in[3];
  const float* b_o    = (const float*)d_in[4];
  const float* sin_t  = (const float*)d_in[5];
  const float* cos_t  = (const float*)d_in[6];
  float* out = (float*)d_out;

  char* ws = (char*)d_ws;
  unsigned short* xn    = (unsigned short*)(ws + (0u << 20));   // 8 MB
  unsigned short* wqkvT = (unsigned short*)(ws + (8u << 20));   // 6 MB
  unsigned short* woT   = (unsigned short*)(ws + (14u << 20));  // 2 MB
  unsigned short* Qh    = (unsigned short*)(ws + (16u << 20));  // 8 MB  [b][h][n][d]
  unsigned short* Kh    = (unsigned short*)(ws + (24u << 20));  // 8 MB
  unsigned short* Vh    = (unsigned short*)(ws + (32u << 20));  // 8 MB
  unsigned short* AO    = (unsigned short*)(ws + (40u << 20));  // 8 MB  [b][n][h*d]

  hipLaunchKernelGGL(k_rmsnorm, dim3(NROWS), dim3(256), 0, stream, x, norm_w, xn);
  hipLaunchKernelGGL(k_transpose_bf16, dim3(16, 48), dim3(256), 0, stream, w_qkv, wqkvT, DMODEL, NQKV);
  hipLaunchKernelGGL(k_transpose_bf16, dim3(16, 16), dim3(256), 0, stream, w_o, woT, DMODEL, DMODEL);
  hipLaunchKernelGGL(k_qkv_gemm, dim3(32, 24), dim3(256), 0, stream, xn, wqkvT, sin_t, cos_t, Qh, Kh, Vh);
  hipLaunchKernelGGL(k_attn, dim3(32, 16), dim3(256), 0, stream, Qh, Kh, Vh, AO);
  hipLaunchKernelGGL(k_out_gemm, dim3(32, 8), dim3(256), 0, stream, AO, woT, b_o, out);
}

// Round 4
// 148.022 us; speedup vs baseline: 1.5561x; 1.0897x over previous
//
#include <hip/hip_runtime.h>
#include <stdint.h>
#include <stddef.h>

#define NTOK   2048
#define NHEAD  16
#define DHEAD  64
#define DMODEL 1024
#define NROWS  4096      // B * NTOK
#define NQKV   3072
#define RMS_EPS 1.1920928955078125e-07f
// attention scale 1/8 with log2(e) folded in (scores in log2 domain)
#define QSCALE 0.1803368801111204f

typedef short bf16x8 __attribute__((ext_vector_type(8)));
typedef float f32x4  __attribute__((ext_vector_type(4)));
typedef unsigned short u16x4 __attribute__((ext_vector_type(4)));

__device__ __forceinline__ unsigned short f2b(float f) {
  unsigned u = __builtin_bit_cast(unsigned, f);
  return (unsigned short)((u + 0x7fffu + ((u >> 16) & 1u)) >> 16);  // RNE
}

__device__ __forceinline__ unsigned pk2bf(float a, float b) {
  return (unsigned)f2b(a) | ((unsigned)f2b(b) << 16);
}

__device__ __forceinline__ void gl16(const void* g, void* l) {
  __builtin_amdgcn_global_load_lds((__attribute__((address_space(1))) void*)g,
                                   (__attribute__((address_space(3))) void*)l,
                                   16, 0, 0);
}

// ---------------- RMSNorm: x fp32 [4096][1024] -> xn bf16 ----------------
__global__ __launch_bounds__(256) void k_rmsnorm(const float* __restrict__ x,
                                                 const float* __restrict__ w,
                                                 unsigned short* __restrict__ xn) {
  int row = blockIdx.x;
  int t = threadIdx.x;
  float4 v = ((const float4*)(x + (size_t)row * DMODEL))[t];
  float ss = v.x * v.x + v.y * v.y + v.z * v.z + v.w * v.w;
#pragma unroll
  for (int m = 1; m < 64; m <<= 1) ss += __shfl_xor(ss, m, 64);
  __shared__ float red[4];
  if ((t & 63) == 0) red[t >> 6] = ss;
  __syncthreads();
  float tot = (red[0] + red[1]) + (red[2] + red[3]);
  float rs = rsqrtf(tot * (1.0f / DMODEL) + RMS_EPS);
  float4 wv = ((const float4*)w)[t];
  u16x4 o;
  o.x = f2b(v.x * rs * wv.x);
  o.y = f2b(v.y * rs * wv.y);
  o.z = f2b(v.z * rs * wv.z);
  o.w = f2b(v.w * rs * wv.w);
  *(u16x4*)(xn + (size_t)row * DMODEL + t * 4) = o;
}

// ------------- transpose+convert: W fp32 [K][Nw] -> Wt bf16 [Nw][K] -------------
__global__ __launch_bounds__(256) void k_transpose_bf16(const float* __restrict__ W,
                                                        unsigned short* __restrict__ Wt,
                                                        int K, int Nw) {
  __shared__ float tile[64][65];
  int bk = blockIdx.x * 64;
  int bn = blockIdx.y * 64;
  int t = threadIdx.x;
  int tr = t >> 4;
  int tc = (t & 15) * 4;
#pragma unroll
  for (int rr = 0; rr < 64; rr += 16) {
    float4 v = *(const float4*)&W[(size_t)(bk + tr + rr) * Nw + bn + tc];
    tile[tr + rr][tc + 0] = v.x;
    tile[tr + rr][tc + 1] = v.y;
    tile[tr + rr][tc + 2] = v.z;
    tile[tr + rr][tc + 3] = v.w;
  }
  __syncthreads();
#pragma unroll
  for (int rr = 0; rr < 64; rr += 16) {
    int n = bn + tr + rr;
    u16x4 o;
    o.x = f2b(tile[tc + 0][tr + rr]);
    o.y = f2b(tile[tc + 1][tr + rr]);
    o.z = f2b(tile[tc + 2][tr + rr]);
    o.w = f2b(tile[tc + 3][tr + rr]);
    *(u16x4*)&Wt[(size_t)n * K + bk + tc] = o;
  }
}

// ---------------- QKV GEMM (m97-style 128x128, BK=32) + fused RoPE ----------------
__global__ __launch_bounds__(256) void k_qkv_gemm(
    const unsigned short* __restrict__ A, const unsigned short* __restrict__ Bt,
    const float* __restrict__ sin_t, const float* __restrict__ cos_t,
    unsigned short* __restrict__ Qh, unsigned short* __restrict__ Kh,
    unsigned short* __restrict__ Vh) {
  __shared__ unsigned short As[128 * 32];
  __shared__ unsigned short Bs[128 * 32];
  int bm = blockIdx.x, bn = blockIdx.y;
  int t = threadIdx.x;
  int l = t & 63, w = t >> 6;
  int wr = w >> 1, wc = w & 1;
  int lr = l & 15, lg = l >> 4;
  f32x4 acc[4][4] = {};

  int srow = t >> 2;
  int scho = (t & 3) * 8;
  const unsigned short* Ag = A + (size_t)(bm * 128 + srow) * DMODEL + scho;
  const unsigned short* Bg = Bt + (size_t)(bn * 128 + srow) * DMODEL + scho;
  unsigned short* lA0 = &As[t * 8];
  unsigned short* lA1 = &As[(t + 256) * 8];
  unsigned short* lB0 = &Bs[t * 8];
  unsigned short* lB1 = &Bs[(t + 256) * 8];

  for (int k0 = 0; k0 < DMODEL; k0 += 32) {
    gl16(Ag + k0, lA0);
    gl16(Ag + k0 + 64 * DMODEL, lA1);
    gl16(Bg + k0, lB0);
    gl16(Bg + k0 + 64 * DMODEL, lB1);
    __syncthreads();
    bf16x8 af[4], bfr[4];
#pragma unroll
    for (int i = 0; i < 4; i++)
      af[i] = *(const bf16x8*)&As[(wr * 64 + i * 16 + lr) * 32 + lg * 8];
#pragma unroll
    for (int j = 0; j < 4; j++)
      bfr[j] = *(const bf16x8*)&Bs[(wc * 64 + j * 16 + lr) * 32 + lg * 8];
#pragma unroll
    for (int i = 0; i < 4; i++)
#pragma unroll
      for (int j = 0; j < 4; j++)
        acc[i][j] = __builtin_amdgcn_mfma_f32_16x16x32_bf16(af[i], bfr[j], acc[i][j], 0, 0, 0);
    __syncthreads();
  }

  int nc0 = bn * 128 + wc * 64;
  int which = nc0 >> 10;
  int h = (nc0 & 1023) >> 6;
#pragma unroll
  for (int i = 0; i < 4; i++) {
#pragma unroll
    for (int r = 0; r < 4; r++) {
      int m = bm * 128 + wr * 64 + i * 16 + lg * 4 + r;
      int b = m >> 11;
      int n = m & (NTOK - 1);
      size_t obase = ((size_t)(b * NHEAD + h) * NTOK + n) * DHEAD;
      if (which == 2) {
#pragma unroll
        for (int j = 0; j < 4; j++) Vh[obase + j * 16 + lr] = f2b(acc[i][j][r]);
      } else {
        unsigned short* dst = which ? Kh : Qh;
        float qs = which ? 1.0f : QSCALE;   // fold attn scale * log2(e) into Q
#pragma unroll
        for (int j = 0; j < 2; j++) {
          int d = j * 16 + lr;
          float t1 = acc[i][j][r];
          float t2 = acc[i][j + 2][r];
          float c1 = cos_t[n * DHEAD + d],      s1 = sin_t[n * DHEAD + d];
          float c2 = cos_t[n * DHEAD + d + 32], s2 = sin_t[n * DHEAD + d + 32];
          dst[obase + d]      = f2b((t1 * c1 - t2 * s1) * qs);
          dst[obase + d + 32] = f2b((t2 * c2 + t1 * s2) * qs);
        }
      }
    }
  }
}

// ---------------- flash attention (causal), dual q-tiles per block ----------------
// Swapped QK^T: S^T = mfma(K_frag, Q_frag) -> lane holds 16 kv-scores of ONE q-row
// (q = lr). Softmax: in-lane reduce + 2 shfl; defer-max skip of rescale; P packed
// and stored as 4x ds_write_b64 into P[q][kv] (XOR-swizzled) = the PV A-layout.
__global__ __launch_bounds__(256) void k_attn(
    const unsigned short* __restrict__ Qh, const unsigned short* __restrict__ Kh,
    const unsigned short* __restrict__ Vh, unsigned short* __restrict__ AO) {
  int bh = blockIdx.x;      // x-major: linear%8 = bh%8 -> same-head blocks share an XCD
  int i  = blockIdx.y;      // 0..15
  int qtA = i, qtB = 31 - i;
  int t = threadIdx.x;
  int l = t & 63, w = t >> 6;
  int lr = l & 15, lg = l >> 4;

  __shared__ unsigned short Ks[2][64 * 64];    // [kv][d], XOR-swizzled rows
  __shared__ unsigned short Vt[2][64 * 64];    // [d][kv], XOR-swizzled rows
  __shared__ unsigned short Ps[4][2][16 * 64]; // per-wave, per-group P[q][kv]

  const unsigned short* Qb = Qh + (size_t)bh * NTOK * DHEAD;
  const unsigned short* Kb = Kh + (size_t)bh * NTOK * DHEAD;
  const unsigned short* Vb = Vh + (size_t)bh * NTOK * DHEAD;

  // group 0 = qtB (always active), group 1 = qtA (active while kt<=qtA)
  int qrow0 = qtB * 64 + w * 16 + lr;
  int qrow1 = qtA * 64 + w * 16 + lr;
  bf16x8 aq0[2], aq1[2];
  aq0[0] = *(const bf16x8*)&Qb[(size_t)qrow0 * DHEAD + lg * 8];
  aq1[0] = *(const bf16x8*)&Qb[(size_t)qrow0 * DHEAD + 32 + lg * 8];
  aq0[1] = *(const bf16x8*)&Qb[(size_t)qrow1 * DHEAD + lg * 8];
  aq1[1] = *(const bf16x8*)&Qb[(size_t)qrow1 * DHEAD + 32 + lg * 8];

  f32x4 accO[2][4] = {};
  float mrow[2] = {-1e38f, -1e38f};   // running max (log2 domain), row q = lr
  float lsum[2] = {0.f, 0.f};

  int srow = t >> 3;           // K staging row 0..31 (+32 second)
  int spc  = t & 7;            // 16B chunk in 128B row
  int vr0  = (t >> 3) * 2;     // V staging row pair

  // ---- prologue: stage tile 0 into buf 0
  gl16(Kb + (size_t)srow * DHEAD + (spc ^ (srow & 7)) * 8, &Ks[0][t * 8]);
  gl16(Kb + (size_t)(srow + 32) * DHEAD + (spc ^ ((srow + 32) & 7)) * 8, &Ks[0][(t + 256) * 8]);
  {
    bf16x8 v0 = *(const bf16x8*)&Vb[(size_t)vr0 * DHEAD + spc * 8];
    bf16x8 v1 = *(const bf16x8*)&Vb[(size_t)(vr0 + 1) * DHEAD + spc * 8];
#pragma unroll
    for (int j = 0; j < 8; j++) {
      int d = spc * 8 + j;
      int sw = ((d & 7) ^ ((d >> 3) & 7)) << 4;
      unsigned pk = (unsigned)(unsigned short)v0[j] | ((unsigned)(unsigned short)v1[j] << 16);
      *(unsigned*)((char*)Vt[0] + d * 128 + ((vr0 * 2) ^ sw)) = pk;
    }
  }
  __syncthreads();

  for (int kt = 0; kt <= qtB; ++kt) {
    int cur = kt & 1, nxt = cur ^ 1;
    int kv0 = kt * 64;
    bool notlast = (kt < qtB);
    bool aAct = (kt <= qtA);

    // ---- issue next-tile staging (lands during this tile's compute)
    bf16x8 pv0, pv1;
    if (notlast) {
      int kvn = kv0 + 64;
      gl16(Kb + (size_t)(kvn + srow) * DHEAD + (spc ^ (srow & 7)) * 8, &Ks[nxt][t * 8]);
      gl16(Kb + (size_t)(kvn + srow + 32) * DHEAD + (spc ^ ((srow + 32) & 7)) * 8,
           &Ks[nxt][(t + 256) * 8]);
      pv0 = *(const bf16x8*)&Vb[(size_t)(kvn + vr0) * DHEAD + spc * 8];
      pv1 = *(const bf16x8*)&Vb[(size_t)(kvn + vr0 + 1) * DHEAD + spc * 8];
    }

    // ---- S^T = K Q^T : lane holds s[kv = nf*16+lg*4+r] for q-row (lr)
    f32x4 s[2][4];
#pragma unroll
    for (int nf = 0; nf < 4; nf++) {
      int krow = nf * 16 + lr;
      const char* kbase = (const char*)Ks[cur] + krow * 128;
      bf16x8 bk0 = *(const bf16x8*)(kbase + ((lg * 16) ^ ((krow & 7) << 4)));
      bf16x8 bk1 = *(const bf16x8*)(kbase + ((lg * 16 + 64) ^ ((krow & 7) << 4)));
      f32x4 z0 = {};
      z0 = __builtin_amdgcn_mfma_f32_16x16x32_bf16(bk0, aq0[0], z0, 0, 0, 0);
      s[0][nf] = __builtin_amdgcn_mfma_f32_16x16x32_bf16(bk1, aq1[0], z0, 0, 0, 0);
      if (aAct) {
        f32x4 z1 = {};
        z1 = __builtin_amdgcn_mfma_f32_16x16x32_bf16(bk0, aq0[1], z1, 0, 0, 0);
        s[1][nf] = __builtin_amdgcn_mfma_f32_16x16x32_bf16(bk1, aq1[1], z1, 0, 0, 0);
      }
    }

    // ---- mask + online softmax (in-lane) + packed P write, per group
#pragma unroll
    for (int g = 0; g < 2; g++) {
      if (g == 0 || aAct) {
        int qtg = g ? qtA : qtB;
        if (kt == qtg) {  // diagonal tile: causal mask
          int qr = qtg * 64 + w * 16 + lr;
#pragma unroll
          for (int nf = 0; nf < 4; nf++)
#pragma unroll
            for (int r = 0; r < 4; r++)
              if (kv0 + nf * 16 + lg * 4 + r > qr) s[g][nf][r] = -1e30f;
        }
        // in-lane max over 16, then reduce across the 4 lanes sharing this q-row
        float pm = fmaxf(fmaxf(fmaxf(s[g][0][0], s[g][0][1]), fmaxf(s[g][0][2], s[g][0][3])),
                         fmaxf(fmaxf(s[g][1][0], s[g][1][1]), fmaxf(s[g][1][2], s[g][1][3])));
        pm = fmaxf(pm, fmaxf(fmaxf(fmaxf(s[g][2][0], s[g][2][1]), fmaxf(s[g][2][2], s[g][2][3])),
                             fmaxf(fmaxf(s[g][3][0], s[g][3][1]), fmaxf(s[g][3][2], s[g][3][3]))));
        pm = fmaxf(pm, __shfl_xor(pm, 16, 64));
        pm = fmaxf(pm, __shfl_xor(pm, 32, 64));
        if (__any(pm > mrow[g] + 8.0f)) {   // defer-max: rescale only on real growth
          float mnew = fmaxf(mrow[g], pm);
          float corr = exp2f(mrow[g] - mnew);
          mrow[g] = mnew;
          lsum[g] *= corr;
          float c0 = __shfl(corr, lg * 4 + 0, 64);
          float c1 = __shfl(corr, lg * 4 + 1, 64);
          float c2 = __shfl(corr, lg * 4 + 2, 64);
          float c3 = __shfl(corr, lg * 4 + 3, 64);
#pragma unroll
          for (int df = 0; df < 4; df++) {
            accO[g][df][0] *= c0; accO[g][df][1] *= c1;
            accO[g][df][2] *= c2; accO[g][df][3] *= c3;
          }
        }
        float m = mrow[g];
        float sum = 0.f;
        char* pw = (char*)Ps[w][g] + lr * 128;
        int sw = (lr & 7) << 4;
#pragma unroll
        for (int nf = 0; nf < 4; nf++) {
          float p0 = exp2f(s[g][nf][0] - m);
          float p1 = exp2f(s[g][nf][1] - m);
          float p2 = exp2f(s[g][nf][2] - m);
          float p3 = exp2f(s[g][nf][3] - m);
          sum += (p0 + p1) + (p2 + p3);
          unsigned w0 = pk2bf(p0, p1);
          unsigned w1 = pk2bf(p2, p3);
          *(uint64_t*)(pw + ((nf * 32 + lg * 8) ^ sw)) = (uint64_t)w0 | ((uint64_t)w1 << 32);
        }
        sum += __shfl_xor(sum, 16, 64);
        sum += __shfl_xor(sum, 32, 64);
        lsum[g] += sum;
      }
    }

    // ---- O += P V : V fragments shared by both groups
#pragma unroll
    for (int ks = 0; ks < 2; ks++) {
      const char* pb0 = (const char*)Ps[w][0] + lr * 128;
      bf16x8 ap0 = *(const bf16x8*)(pb0 + ((lg * 16 + ks * 64) ^ ((lr & 7) << 4)));
      bf16x8 ap1;
      if (aAct) {
        const char* pb1 = (const char*)Ps[w][1] + lr * 128;
        ap1 = *(const bf16x8*)(pb1 + ((lg * 16 + ks * 64) ^ ((lr & 7) << 4)));
      }
#pragma unroll
      for (int df = 0; df < 4; df++) {
        int col = df * 16 + lr;
        int sw = ((col & 7) ^ ((col >> 3) & 7)) << 4;
        bf16x8 bv = *(const bf16x8*)((const char*)Vt[cur] + col * 128 + ((lg * 16 + ks * 64) ^ sw));
        accO[0][df] = __builtin_amdgcn_mfma_f32_16x16x32_bf16(ap0, bv, accO[0][df], 0, 0, 0);
        if (aAct)
          accO[1][df] = __builtin_amdgcn_mfma_f32_16x16x32_bf16(ap1, bv, accO[1][df], 0, 0, 0);
      }
    }

    // ---- write-late: prefetched V regs -> LDS (vmcnt wait lands here, after PV)
    if (notlast) {
#pragma unroll
      for (int j = 0; j < 8; j++) {
        int d = spc * 8 + j;
        int sw = ((d & 7) ^ ((d >> 3) & 7)) << 4;
        unsigned pk = (unsigned)(unsigned short)pv0[j] | ((unsigned)(unsigned short)pv1[j] << 16);
        *(unsigned*)((char*)Vt[nxt] + d * 128 + ((vr0 * 2) ^ sw)) = pk;
      }
    }
    __syncthreads();
  }

  // ---- epilogue: normalize (stats live at q=lr; broadcast to acc rows), write
  int b = bh >> 4, h = bh & 15;
#pragma unroll
  for (int g = 0; g < 2; g++) {
    float li = 1.0f / lsum[g];
    float l0 = __shfl(li, lg * 4 + 0, 64);
    float l1 = __shfl(li, lg * 4 + 1, 64);
    float l2 = __shfl(li, lg * 4 + 2, 64);
    float l3 = __shfl(li, lg * 4 + 3, 64);
    int qbase = (g ? qtA : qtB) * 64 + w * 16;
#pragma unroll
    for (int df = 0; df < 4; df++) {
      int d = df * 16 + lr;
      size_t ob = ((size_t)(b * NTOK + qbase + lg * 4)) * DMODEL + h * DHEAD + d;
      AO[ob + 0 * DMODEL] = f2b(accO[g][df][0] * l0);
      AO[ob + 1 * DMODEL] = f2b(accO[g][df][1] * l1);
      AO[ob + 2 * DMODEL] = f2b(accO[g][df][2] * l2);
      AO[ob + 3 * DMODEL] = f2b(accO[g][df][3] * l3);
    }
  }
}

// ---------------- out GEMM: AO bf16 [4096][1024] @ w_o^T + bias -> fp32 ----------------
__global__ __launch_bounds__(256) void k_out_gemm(
    const unsigned short* __restrict__ A, const unsigned short* __restrict__ Bt,
    const float* __restrict__ bias, float* __restrict__ out) {
  __shared__ unsigned short As[128 * 32];
  __shared__ unsigned short Bs[128 * 32];
  int bm = blockIdx.x, bn = blockIdx.y;
  int t = threadIdx.x;
  int l = t & 63, w = t >> 6;
  int wr = w >> 1, wc = w & 1;
  int lr = l & 15, lg = l >> 4;
  f32x4 acc[4][4] = {};

  int srow = t >> 2;
  int scho = (t & 3) * 8;
  const unsigned short* Ag = A + (size_t)(bm * 128 + srow) * DMODEL + scho;
  const unsigned short* Bg = Bt + (size_t)(bn * 128 + srow) * DMODEL + scho;
  unsigned short* lA0 = &As[t * 8];
  unsigned short* lA1 = &As[(t + 256) * 8];
  unsigned short* lB0 = &Bs[t * 8];
  unsigned short* lB1 = &Bs[(t + 256) * 8];

  for (int k0 = 0; k0 < DMODEL; k0 += 32) {
    gl16(Ag + k0, lA0);
    gl16(Ag + k0 + 64 * DMODEL, lA1);
    gl16(Bg + k0, lB0);
    gl16(Bg + k0 + 64 * DMODEL, lB1);
    __syncthreads();
    bf16x8 af[4], bfr[4];
#pragma unroll
    for (int i = 0; i < 4; i++)
      af[i] = *(const bf16x8*)&As[(wr * 64 + i * 16 + lr) * 32 + lg * 8];
#pragma unroll
    for (int j = 0; j < 4; j++)
      bfr[j] = *(const bf16x8*)&Bs[(wc * 64 + j * 16 + lr) * 32 + lg * 8];
#pragma unroll
    for (int i = 0; i < 4; i++)
#pragma unroll
      for (int j = 0; j < 4; j++)
        acc[i][j] = __builtin_amdgcn_mfma_f32_16x16x32_bf16(af[i], bfr[j], acc[i][j], 0, 0, 0);
    __syncthreads();
  }
  int nc0 = bn * 128 + wc * 64;
#pragma unroll
  for (int i = 0; i < 4; i++)
#pragma unroll
    for (int r = 0; r < 4; r++) {
      int m = bm * 128 + wr * 64 + i * 16 + lg * 4 + r;
      float* orow = out + (size_t)m * DMODEL;
#pragma unroll
      for (int j = 0; j < 4; j++) {
        int col = nc0 + j * 16 + lr;
        orow[col] = acc[i][j][r] + bias[col];
      }
    }
}

extern "C" void kernel_launch(void* const* d_in, const int* in_sizes, int n_in,
                              void* d_out, int out_size, void* d_ws, size_t ws_size,
                              hipStream_t stream) {
  const float* x      = (const float*)d_in[0];
  const float* norm_w = (const float*)d_in[1];
  const float* w_qkv  = (const float*)d_in[2];
  const float* w_o    = (const float*)d_in[3];
  const float* b_o    = (const float*)d_in[4];
  const float* sin_t  = (const float*)d_in[5];
  const float* cos_t  = (const float*)d_in[6];
  float* out = (float*)d_out;

  char* ws = (char*)d_ws;
  unsigned short* xn    = (unsigned short*)(ws + (0u << 20));   // 8 MB
  unsigned short* wqkvT = (unsigned short*)(ws + (8u << 20));   // 6 MB
  unsigned short* woT   = (unsigned short*)(ws + (14u << 20));  // 2 MB
  unsigned short* Qh    = (unsigned short*)(ws + (16u << 20));  // 8 MB  [b][h][n][d]
  unsigned short* Kh    = (unsigned short*)(ws + (24u << 20));  // 8 MB
  unsigned short* Vh    = (unsigned short*)(ws + (32u << 20));  // 8 MB
  unsigned short* AO    = (unsigned short*)(ws + (40u << 20));  // 8 MB  [b][n][h*d]

  hipLaunchKernelGGL(k_rmsnorm, dim3(NROWS), dim3(256), 0, stream, x, norm_w, xn);
  hipLaunchKernelGGL(k_transpose_bf16, dim3(16, 48), dim3(256), 0, stream, w_qkv, wqkvT, DMODEL, NQKV);
  hipLaunchKernelGGL(k_transpose_bf16, dim3(16, 16), dim3(256), 0, stream, w_o, woT, DMODEL, DMODEL);
  hipLaunchKernelGGL(k_qkv_gemm, dim3(32, 24), dim3(256), 0, stream, xn, wqkvT, sin_t, cos_t, Qh, Kh, Vh);
  hipLaunchKernelGGL(k_attn, dim3(32, 16), dim3(256), 0, stream, Qh, Kh, Vh, AO);
  hipLaunchKernelGGL(k_out_gemm, dim3(32, 8), dim3(256), 0, stream, AO, woT, b_o, out);
}

// Round 5
// 135.738 us; speedup vs baseline: 1.6969x; 1.0905x over previous
//
#include <hip/hip_runtime.h>
#include <hip/hip_bf16.h>
#include <stdint.h>
#include <stddef.h>

#define NTOK   2048
#define NHEAD  16
#define DHEAD  64
#define DMODEL 1024
#define NROWS  4096      // B * NTOK
#define NQKV   3072
#define RMS_EPS 1.1920928955078125e-07f
// attention scale 1/8 with log2(e) folded in (scores in log2 domain)
#define QSCALE 0.1803368801111204f

typedef short bf16x8 __attribute__((ext_vector_type(8)));
typedef float f32x4  __attribute__((ext_vector_type(4)));
typedef unsigned short u16x4 __attribute__((ext_vector_type(4)));

__device__ __forceinline__ unsigned short f2b(float f) {
  unsigned u = __builtin_bit_cast(unsigned, f);
  return (unsigned short)((u + 0x7fffu + ((u >> 16) & 1u)) >> 16);  // RNE
}

// packed f32x2 -> bf16x2; __float22bfloat162_rn lowers to v_cvt_pk_bf16_f32 on gfx950
__device__ __forceinline__ unsigned pk2bf(float a, float b) {
  __hip_bfloat162 h = __float22bfloat162_rn(make_float2(a, b));
  unsigned u;
  __builtin_memcpy(&u, &h, 4);
  return u;
}

__device__ __forceinline__ void gl16(const void* g, void* l) {
  __builtin_amdgcn_global_load_lds((__attribute__((address_space(1))) void*)g,
                                   (__attribute__((address_space(3))) void*)l,
                                   16, 0, 0);
}

// ---------------- RMSNorm: x fp32 [4096][1024] -> xn bf16 ----------------
__global__ __launch_bounds__(256) void k_rmsnorm(const float* __restrict__ x,
                                                 const float* __restrict__ w,
                                                 unsigned short* __restrict__ xn) {
  int row = blockIdx.x;
  int t = threadIdx.x;
  float4 v = ((const float4*)(x + (size_t)row * DMODEL))[t];
  float ss = v.x * v.x + v.y * v.y + v.z * v.z + v.w * v.w;
#pragma unroll
  for (int m = 1; m < 64; m <<= 1) ss += __shfl_xor(ss, m, 64);
  __shared__ float red[4];
  if ((t & 63) == 0) red[t >> 6] = ss;
  __syncthreads();
  float tot = (red[0] + red[1]) + (red[2] + red[3]);
  float rs = rsqrtf(tot * (1.0f / DMODEL) + RMS_EPS);
  float4 wv = ((const float4*)w)[t];
  u16x4 o;
  o.x = f2b(v.x * rs * wv.x);
  o.y = f2b(v.y * rs * wv.y);
  o.z = f2b(v.z * rs * wv.z);
  o.w = f2b(v.w * rs * wv.w);
  *(u16x4*)(xn + (size_t)row * DMODEL + t * 4) = o;
}

// ------------- transpose+convert: W fp32 [K][Nw] -> Wt bf16 [Nw][K] -------------
__global__ __launch_bounds__(256) void k_transpose_bf16(const float* __restrict__ W,
                                                        unsigned short* __restrict__ Wt,
                                                        int K, int Nw) {
  __shared__ float tile[64][65];
  int bk = blockIdx.x * 64;
  int bn = blockIdx.y * 64;
  int t = threadIdx.x;
  int tr = t >> 4;
  int tc = (t & 15) * 4;
#pragma unroll
  for (int rr = 0; rr < 64; rr += 16) {
    float4 v = *(const float4*)&W[(size_t)(bk + tr + rr) * Nw + bn + tc];
    tile[tr + rr][tc + 0] = v.x;
    tile[tr + rr][tc + 1] = v.y;
    tile[tr + rr][tc + 2] = v.z;
    tile[tr + rr][tc + 3] = v.w;
  }
  __syncthreads();
#pragma unroll
  for (int rr = 0; rr < 64; rr += 16) {
    int n = bn + tr + rr;
    u16x4 o;
    o.x = f2b(tile[tc + 0][tr + rr]);
    o.y = f2b(tile[tc + 1][tr + rr]);
    o.z = f2b(tile[tc + 2][tr + rr]);
    o.w = f2b(tile[tc + 3][tr + rr]);
    *(u16x4*)&Wt[(size_t)n * K + bk + tc] = o;
  }
}

// ---------------- QKV GEMM (m97-style 128x128, BK=32) + fused RoPE ----------------
__global__ __launch_bounds__(256) void k_qkv_gemm(
    const unsigned short* __restrict__ A, const unsigned short* __restrict__ Bt,
    const float* __restrict__ sin_t, const float* __restrict__ cos_t,
    unsigned short* __restrict__ Qh, unsigned short* __restrict__ Kh,
    unsigned short* __restrict__ Vh) {
  __shared__ unsigned short As[128 * 32];
  __shared__ unsigned short Bs[128 * 32];
  int bm = blockIdx.x, bn = blockIdx.y;
  int t = threadIdx.x;
  int l = t & 63, w = t >> 6;
  int wr = w >> 1, wc = w & 1;
  int lr = l & 15, lg = l >> 4;
  f32x4 acc[4][4] = {};

  int srow = t >> 2;
  int scho = (t & 3) * 8;
  const unsigned short* Ag = A + (size_t)(bm * 128 + srow) * DMODEL + scho;
  const unsigned short* Bg = Bt + (size_t)(bn * 128 + srow) * DMODEL + scho;
  unsigned short* lA0 = &As[t * 8];
  unsigned short* lA1 = &As[(t + 256) * 8];
  unsigned short* lB0 = &Bs[t * 8];
  unsigned short* lB1 = &Bs[(t + 256) * 8];

  for (int k0 = 0; k0 < DMODEL; k0 += 32) {
    gl16(Ag + k0, lA0);
    gl16(Ag + k0 + 64 * DMODEL, lA1);
    gl16(Bg + k0, lB0);
    gl16(Bg + k0 + 64 * DMODEL, lB1);
    __syncthreads();
    bf16x8 af[4], bfr[4];
#pragma unroll
    for (int i = 0; i < 4; i++)
      af[i] = *(const bf16x8*)&As[(wr * 64 + i * 16 + lr) * 32 + lg * 8];
#pragma unroll
    for (int j = 0; j < 4; j++)
      bfr[j] = *(const bf16x8*)&Bs[(wc * 64 + j * 16 + lr) * 32 + lg * 8];
#pragma unroll
    for (int i = 0; i < 4; i++)
#pragma unroll
      for (int j = 0; j < 4; j++)
        acc[i][j] = __builtin_amdgcn_mfma_f32_16x16x32_bf16(af[i], bfr[j], acc[i][j], 0, 0, 0);
    __syncthreads();
  }

  int nc0 = bn * 128 + wc * 64;
  int which = nc0 >> 10;
  int h = (nc0 & 1023) >> 6;
#pragma unroll
  for (int i = 0; i < 4; i++) {
#pragma unroll
    for (int r = 0; r < 4; r++) {
      int m = bm * 128 + wr * 64 + i * 16 + lg * 4 + r;
      int b = m >> 11;
      int n = m & (NTOK - 1);
      size_t obase = ((size_t)(b * NHEAD + h) * NTOK + n) * DHEAD;
      if (which == 2) {
#pragma unroll
        for (int j = 0; j < 4; j++) Vh[obase + j * 16 + lr] = f2b(acc[i][j][r]);
      } else {
        unsigned short* dst = which ? Kh : Qh;
        float qs = which ? 1.0f : QSCALE;   // fold attn scale * log2(e) into Q
#pragma unroll
        for (int j = 0; j < 2; j++) {
          int d = j * 16 + lr;
          float t1 = acc[i][j][r];
          float t2 = acc[i][j + 2][r];
          float c1 = cos_t[n * DHEAD + d],      s1 = sin_t[n * DHEAD + d];
          float c2 = cos_t[n * DHEAD + d + 32], s2 = sin_t[n * DHEAD + d + 32];
          dst[obase + d]      = f2b((t1 * c1 - t2 * s1) * qs);
          dst[obase + d + 32] = f2b((t2 * c2 + t1 * s2) * qs);
        }
      }
    }
  }
}

// ---------------- flash attention (causal), 1 q-tile (64 rows) per block ----------------
// Grid 32(bh) x 32(j). Balanced j->qt mapping: classes {j = m mod 8} cover one qt from
// each quartile {31-m, m, 23-m, 8+m} so any round-robin CU assignment gets ~equal work.
// 40KB LDS -> 4 blocks/CU = 16 waves/CU. Swapped QK^T + in-lane softmax (q-row = lr),
// defer-max, hw cvt_pk P-packing, double-buffered K (global_load_lds) and V (reg, write-late).
__global__ __launch_bounds__(256, 4) void k_attn(
    const unsigned short* __restrict__ Qh, const unsigned short* __restrict__ Kh,
    const unsigned short* __restrict__ Vh, unsigned short* __restrict__ AO) {
  int bh = blockIdx.x;      // x-major: linear%8 = bh%8 -> same-head blocks share an XCD
  int j  = blockIdx.y;
  int m8 = j & 7, k8 = j >> 3;
  int qt = (k8 == 0) ? 31 - m8 : (k8 == 1) ? m8 : (k8 == 2) ? 23 - m8 : 8 + m8;
  int t = threadIdx.x;
  int l = t & 63, w = t >> 6;
  int lr = l & 15, lg = l >> 4;

  __shared__ unsigned short Ks[2][64 * 64];  // [kv][d], XOR-swizzled rows   (16 KB)
  __shared__ unsigned short Vt[2][64 * 64];  // [d][kv], XOR-swizzled rows   (16 KB)
  __shared__ unsigned short Ps[4][16 * 64];  // per-wave P[q][kv]            ( 8 KB)

  const unsigned short* Qb = Qh + (size_t)bh * NTOK * DHEAD;
  const unsigned short* Kb = Kh + (size_t)bh * NTOK * DHEAD;
  const unsigned short* Vb = Vh + (size_t)bh * NTOK * DHEAD;

  int qrow = qt * 64 + w * 16 + lr;
  bf16x8 aq0 = *(const bf16x8*)&Qb[(size_t)qrow * DHEAD + lg * 8];
  bf16x8 aq1 = *(const bf16x8*)&Qb[(size_t)qrow * DHEAD + 32 + lg * 8];

  f32x4 accO[4] = {};
  float mrow = -1e38f;    // running max (log2 domain), q-row = lr
  float lsum = 0.f;

  int srow = t >> 3;           // K staging row 0..31 (+32 second)
  int spc  = t & 7;            // 16B chunk in 128B row
  int vr0  = (t >> 3) * 2;     // V staging row pair

  // ---- prologue: stage tile 0 into buf 0
  gl16(Kb + (size_t)srow * DHEAD + (spc ^ (srow & 7)) * 8, &Ks[0][t * 8]);
  gl16(Kb + (size_t)(srow + 32) * DHEAD + (spc ^ ((srow + 32) & 7)) * 8, &Ks[0][(t + 256) * 8]);
  {
    bf16x8 v0 = *(const bf16x8*)&Vb[(size_t)vr0 * DHEAD + spc * 8];
    bf16x8 v1 = *(const bf16x8*)&Vb[(size_t)(vr0 + 1) * DHEAD + spc * 8];
#pragma unroll
    for (int jj = 0; jj < 8; jj++) {
      int d = spc * 8 + jj;
      int sw = ((d & 7) ^ ((d >> 3) & 7)) << 4;
      unsigned pk = (unsigned)(unsigned short)v0[jj] | ((unsigned)(unsigned short)v1[jj] << 16);
      *(unsigned*)((char*)Vt[0] + d * 128 + ((vr0 * 2) ^ sw)) = pk;
    }
  }
  __syncthreads();

  for (int kt = 0; kt <= qt; ++kt) {
    int cur = kt & 1, nxt = cur ^ 1;
    int kv0 = kt * 64;
    bool notlast = (kt < qt);

    // ---- issue next-tile staging (lands during this tile's compute)
    bf16x8 pv0, pv1;
    if (notlast) {
      int kvn = kv0 + 64;
      gl16(Kb + (size_t)(kvn + srow) * DHEAD + (spc ^ (srow & 7)) * 8, &Ks[nxt][t * 8]);
      gl16(Kb + (size_t)(kvn + srow + 32) * DHEAD + (spc ^ ((srow + 32) & 7)) * 8,
           &Ks[nxt][(t + 256) * 8]);
      pv0 = *(const bf16x8*)&Vb[(size_t)(kvn + vr0) * DHEAD + spc * 8];
      pv1 = *(const bf16x8*)&Vb[(size_t)(kvn + vr0 + 1) * DHEAD + spc * 8];
    }

    // ---- S^T = K Q^T : lane holds s[kv = nf*16+lg*4+r] for q-row (lr)
    f32x4 s[4];
#pragma unroll
    for (int nf = 0; nf < 4; nf++) {
      int krow = nf * 16 + lr;
      const char* kbase = (const char*)Ks[cur] + krow * 128;
      bf16x8 bk0 = *(const bf16x8*)(kbase + ((lg * 16) ^ ((krow & 7) << 4)));
      bf16x8 bk1 = *(const bf16x8*)(kbase + ((lg * 16 + 64) ^ ((krow & 7) << 4)));
      f32x4 z = {};
      z = __builtin_amdgcn_mfma_f32_16x16x32_bf16(bk0, aq0, z, 0, 0, 0);
      s[nf] = __builtin_amdgcn_mfma_f32_16x16x32_bf16(bk1, aq1, z, 0, 0, 0);
    }

    // ---- causal mask (diagonal tile only)
    if (kt == qt) {
      int qr = qt * 64 + w * 16 + lr;
#pragma unroll
      for (int nf = 0; nf < 4; nf++)
#pragma unroll
        for (int r = 0; r < 4; r++)
          if (kv0 + nf * 16 + lg * 4 + r > qr) s[nf][r] = -1e30f;
    }

    // ---- online softmax: in-lane max (v_max3 trees) + 2 shfl across q-row group
    float t1m = fmaxf(fmaxf(s[0][0], s[0][1]), s[0][2]);
    float t2m = fmaxf(fmaxf(s[0][3], s[1][0]), s[1][1]);
    float t3m = fmaxf(fmaxf(s[1][2], s[1][3]), s[2][0]);
    float t4m = fmaxf(fmaxf(s[2][1], s[2][2]), s[2][3]);
    float t5m = fmaxf(fmaxf(s[3][0], s[3][1]), s[3][2]);
    float pm = fmaxf(fmaxf(fmaxf(t1m, t2m), t3m), fmaxf(fmaxf(t4m, t5m), s[3][3]));
    pm = fmaxf(pm, __shfl_xor(pm, 16, 64));
    pm = fmaxf(pm, __shfl_xor(pm, 32, 64));
    if (__any(pm > mrow + 8.0f)) {   // defer-max: rescale only on real growth
      float mnew = fmaxf(mrow, pm);
      float corr = exp2f(mrow - mnew);
      mrow = mnew;
      lsum *= corr;
      float c0 = __shfl(corr, lg * 4 + 0, 64);
      float c1 = __shfl(corr, lg * 4 + 1, 64);
      float c2 = __shfl(corr, lg * 4 + 2, 64);
      float c3 = __shfl(corr, lg * 4 + 3, 64);
#pragma unroll
      for (int df = 0; df < 4; df++) {
        accO[df][0] *= c0; accO[df][1] *= c1;
        accO[df][2] *= c2; accO[df][3] *= c3;
      }
    }
    {
      float m = mrow;
      float sum = 0.f;
      char* pw = (char*)Ps[w] + lr * 128;
      int sw = (lr & 7) << 4;
#pragma unroll
      for (int nf = 0; nf < 4; nf++) {
        float p0 = exp2f(s[nf][0] - m);
        float p1 = exp2f(s[nf][1] - m);
        float p2 = exp2f(s[nf][2] - m);
        float p3 = exp2f(s[nf][3] - m);
        sum += (p0 + p1) + (p2 + p3);
        unsigned w0 = pk2bf(p0, p1);
        unsigned w1 = pk2bf(p2, p3);
        *(uint64_t*)(pw + ((nf * 32 + lg * 8) ^ sw)) = (uint64_t)w0 | ((uint64_t)w1 << 32);
      }
      sum += __shfl_xor(sum, 16, 64);
      sum += __shfl_xor(sum, 32, 64);
      lsum += sum;
    }

    // ---- O += P V
#pragma unroll
    for (int ks = 0; ks < 2; ks++) {
      const char* pb = (const char*)Ps[w] + lr * 128;
      bf16x8 ap = *(const bf16x8*)(pb + ((lg * 16 + ks * 64) ^ ((lr & 7) << 4)));
#pragma unroll
      for (int df = 0; df < 4; df++) {
        int col = df * 16 + lr;
        int sw = ((col & 7) ^ ((col >> 3) & 7)) << 4;
        bf16x8 bv = *(const bf16x8*)((const char*)Vt[cur] + col * 128 + ((lg * 16 + ks * 64) ^ sw));
        accO[df] = __builtin_amdgcn_mfma_f32_16x16x32_bf16(ap, bv, accO[df], 0, 0, 0);
      }
    }

    // ---- write-late: prefetched V regs -> LDS (vmcnt wait lands here, after PV)
    if (notlast) {
#pragma unroll
      for (int jj = 0; jj < 8; jj++) {
        int d = spc * 8 + jj;
        int sw = ((d & 7) ^ ((d >> 3) & 7)) << 4;
        unsigned pk = (unsigned)(unsigned short)pv0[jj] | ((unsigned)(unsigned short)pv1[jj] << 16);
        *(unsigned*)((char*)Vt[nxt] + d * 128 + ((vr0 * 2) ^ sw)) = pk;
      }
    }
    __syncthreads();
  }

  // ---- epilogue: normalize (stats live at q=lr; broadcast to acc rows), write
  int b = bh >> 4, h = bh & 15;
  float li = 1.0f / lsum;
  float l0 = __shfl(li, lg * 4 + 0, 64);
  float l1 = __shfl(li, lg * 4 + 1, 64);
  float l2 = __shfl(li, lg * 4 + 2, 64);
  float l3 = __shfl(li, lg * 4 + 3, 64);
  int qbase = qt * 64 + w * 16;
#pragma unroll
  for (int df = 0; df < 4; df++) {
    int d = df * 16 + lr;
    size_t ob = ((size_t)(b * NTOK + qbase + lg * 4)) * DMODEL + h * DHEAD + d;
    AO[ob + 0 * DMODEL] = f2b(accO[df][0] * l0);
    AO[ob + 1 * DMODEL] = f2b(accO[df][1] * l1);
    AO[ob + 2 * DMODEL] = f2b(accO[df][2] * l2);
    AO[ob + 3 * DMODEL] = f2b(accO[df][3] * l3);
  }
}

// ---------------- out GEMM: AO bf16 [4096][1024] @ w_o^T + bias -> fp32 ----------------
__global__ __launch_bounds__(256) void k_out_gemm(
    const unsigned short* __restrict__ A, const unsigned short* __restrict__ Bt,
    const float* __restrict__ bias, float* __restrict__ out) {
  __shared__ unsigned short As[128 * 32];
  __shared__ unsigned short Bs[128 * 32];
  int bm = blockIdx.x, bn = blockIdx.y;
  int t = threadIdx.x;
  int l = t & 63, w = t >> 6;
  int wr = w >> 1, wc = w & 1;
  int lr = l & 15, lg = l >> 4;
  f32x4 acc[4][4] = {};

  int srow = t >> 2;
  int scho = (t & 3) * 8;
  const unsigned short* Ag = A + (size_t)(bm * 128 + srow) * DMODEL + scho;
  const unsigned short* Bg = Bt + (size_t)(bn * 128 + srow) * DMODEL + scho;
  unsigned short* lA0 = &As[t * 8];
  unsigned short* lA1 = &As[(t + 256) * 8];
  unsigned short* lB0 = &Bs[t * 8];
  unsigned short* lB1 = &Bs[(t + 256) * 8];

  for (int k0 = 0; k0 < DMODEL; k0 += 32) {
    gl16(Ag + k0, lA0);
    gl16(Ag + k0 + 64 * DMODEL, lA1);
    gl16(Bg + k0, lB0);
    gl16(Bg + k0 + 64 * DMODEL, lB1);
    __syncthreads();
    bf16x8 af[4], bfr[4];
#pragma unroll
    for (int i = 0; i < 4; i++)
      af[i] = *(const bf16x8*)&As[(wr * 64 + i * 16 + lr) * 32 + lg * 8];
#pragma unroll
    for (int j = 0; j < 4; j++)
      bfr[j] = *(const bf16x8*)&Bs[(wc * 64 + j * 16 + lr) * 32 + lg * 8];
#pragma unroll
    for (int i = 0; i < 4; i++)
#pragma unroll
      for (int j = 0; j < 4; j++)
        acc[i][j] = __builtin_amdgcn_mfma_f32_16x16x32_bf16(af[i], bfr[j], acc[i][j], 0, 0, 0);
    __syncthreads();
  }
  int nc0 = bn * 128 + wc * 64;
#pragma unroll
  for (int i = 0; i < 4; i++)
#pragma unroll
    for (int r = 0; r < 4; r++) {
      int m = bm * 128 + wr * 64 + i * 16 + lg * 4 + r;
      float* orow = out + (size_t)m * DMODEL;
#pragma unroll
      for (int j = 0; j < 4; j++) {
        int col = nc0 + j * 16 + lr;
        orow[col] = acc[i][j][r] + bias[col];
      }
    }
}

extern "C" void kernel_launch(void* const* d_in, const int* in_sizes, int n_in,
                              void* d_out, int out_size, void* d_ws, size_t ws_size,
                              hipStream_t stream) {
  const float* x      = (const float*)d_in[0];
  const float* norm_w = (const float*)d_in[1];
  const float* w_qkv  = (const float*)d_in[2];
  const float* w_o    = (const float*)d_in[3];
  const float* b_o    = (const float*)d_in[4];
  const float* sin_t  = (const float*)d_in[5];
  const float* cos_t  = (const float*)d_in[6];
  float* out = (float*)d_out;

  char* ws = (char*)d_ws;
  unsigned short* xn    = (unsigned short*)(ws + (0u << 20));   // 8 MB
  unsigned short* wqkvT = (unsigned short*)(ws + (8u << 20));   // 6 MB
  unsigned short* woT   = (unsigned short*)(ws + (14u << 20));  // 2 MB
  unsigned short* Qh    = (unsigned short*)(ws + (16u << 20));  // 8 MB  [b][h][n][d]
  unsigned short* Kh    = (unsigned short*)(ws + (24u << 20));  // 8 MB
  unsigned short* Vh    = (unsigned short*)(ws + (32u << 20));  // 8 MB
  unsigned short* AO    = (unsigned short*)(ws + (40u << 20));  // 8 MB  [b][n][h*d]

  hipLaunchKernelGGL(k_rmsnorm, dim3(NROWS), dim3(256), 0, stream, x, norm_w, xn);
  hipLaunchKernelGGL(k_transpose_bf16, dim3(16, 48), dim3(256), 0, stream, w_qkv, wqkvT, DMODEL, NQKV);
  hipLaunchKernelGGL(k_transpose_bf16, dim3(16, 16), dim3(256), 0, stream, w_o, woT, DMODEL, DMODEL);
  hipLaunchKernelGGL(k_qkv_gemm, dim3(32, 24), dim3(256), 0, stream, xn, wqkvT, sin_t, cos_t, Qh, Kh, Vh);
  hipLaunchKernelGGL(k_attn, dim3(32, 32), dim3(256), 0, stream, Qh, Kh, Vh, AO);
  hipLaunchKernelGGL(k_out_gemm, dim3(32, 8), dim3(256), 0, stream, AO, woT, b_o, out);
}

// Round 6
// 120.452 us; speedup vs baseline: 1.9122x; 1.1269x over previous
//
#include <hip/hip_runtime.h>
#include <hip/hip_bf16.h>
#include <stdint.h>
#include <stddef.h>

#define NTOK   2048
#define NHEAD  16
#define DHEAD  64
#define DMODEL 1024
#define NROWS  4096      // B * NTOK
#define NQKV   3072
#define RMS_EPS 1.1920928955078125e-07f
// attention scale 1/8 with log2(e) folded in (scores in log2 domain)
#define QSCALE 0.1803368801111204f

typedef short bf16x8 __attribute__((ext_vector_type(8)));
typedef float f32x4  __attribute__((ext_vector_type(4)));
typedef unsigned short u16x4 __attribute__((ext_vector_type(4)));

__device__ __forceinline__ unsigned short f2b(float f) {
  unsigned u = __builtin_bit_cast(unsigned, f);
  return (unsigned short)((u + 0x7fffu + ((u >> 16) & 1u)) >> 16);  // RNE
}

// packed f32x2 -> bf16x2
__device__ __forceinline__ unsigned pk2bf(float a, float b) {
  __hip_bfloat162 h = __float22bfloat162_rn(make_float2(a, b));
  unsigned u;
  __builtin_memcpy(&u, &h, 4);
  return u;
}

__device__ __forceinline__ void gl16(const void* g, void* l) {
  __builtin_amdgcn_global_load_lds((__attribute__((address_space(1))) void*)g,
                                   (__attribute__((address_space(3))) void*)l,
                                   16, 0, 0);
}

// ---------------- RMSNorm: x fp32 [4096][1024] -> xn bf16 ----------------
__global__ __launch_bounds__(256) void k_rmsnorm(const float* __restrict__ x,
                                                 const float* __restrict__ w,
                                                 unsigned short* __restrict__ xn) {
  int row = blockIdx.x;
  int t = threadIdx.x;
  float4 v = ((const float4*)(x + (size_t)row * DMODEL))[t];
  float ss = v.x * v.x + v.y * v.y + v.z * v.z + v.w * v.w;
#pragma unroll
  for (int m = 1; m < 64; m <<= 1) ss += __shfl_xor(ss, m, 64);
  __shared__ float red[4];
  if ((t & 63) == 0) red[t >> 6] = ss;
  __syncthreads();
  float tot = (red[0] + red[1]) + (red[2] + red[3]);
  float rs = rsqrtf(tot * (1.0f / DMODEL) + RMS_EPS);
  float4 wv = ((const float4*)w)[t];
  u16x4 o;
  o.x = f2b(v.x * rs * wv.x);
  o.y = f2b(v.y * rs * wv.y);
  o.z = f2b(v.z * rs * wv.z);
  o.w = f2b(v.w * rs * wv.w);
  *(u16x4*)(xn + (size_t)row * DMODEL + t * 4) = o;
}

// ------------- transpose+convert: W fp32 [K][Nw] -> Wt bf16 [Nw][K] -------------
__global__ __launch_bounds__(256) void k_transpose_bf16(const float* __restrict__ W,
                                                        unsigned short* __restrict__ Wt,
                                                        int K, int Nw) {
  __shared__ float tile[64][65];
  int bk = blockIdx.x * 64;
  int bn = blockIdx.y * 64;
  int t = threadIdx.x;
  int tr = t >> 4;
  int tc = (t & 15) * 4;
#pragma unroll
  for (int rr = 0; rr < 64; rr += 16) {
    float4 v = *(const float4*)&W[(size_t)(bk + tr + rr) * Nw + bn + tc];
    tile[tr + rr][tc + 0] = v.x;
    tile[tr + rr][tc + 1] = v.y;
    tile[tr + rr][tc + 2] = v.z;
    tile[tr + rr][tc + 3] = v.w;
  }
  __syncthreads();
#pragma unroll
  for (int rr = 0; rr < 64; rr += 16) {
    int n = bn + tr + rr;
    u16x4 o;
    o.x = f2b(tile[tc + 0][tr + rr]);
    o.y = f2b(tile[tc + 1][tr + rr]);
    o.z = f2b(tile[tc + 2][tr + rr]);
    o.w = f2b(tile[tc + 3][tr + rr]);
    *(u16x4*)&Wt[(size_t)n * K + bk + tc] = o;
  }
}

// ------- QKV GEMM (128x128, BK=32, T3 2-phase double-buffered) + fused RoPE -------
__global__ __launch_bounds__(256) void k_qkv_gemm(
    const unsigned short* __restrict__ A, const unsigned short* __restrict__ Bt,
    const float* __restrict__ sin_t, const float* __restrict__ cos_t,
    unsigned short* __restrict__ Qh, unsigned short* __restrict__ Kh,
    unsigned short* __restrict__ Vh) {
  __shared__ unsigned short As[2][128 * 32];
  __shared__ unsigned short Bs[2][128 * 32];
  int bm = blockIdx.x, bn = blockIdx.y;
  int t = threadIdx.x;
  int l = t & 63, w = t >> 6;
  int wr = w >> 1, wc = w & 1;
  int lr = l & 15, lg = l >> 4;
  f32x4 acc[4][4] = {};

  int srow = t >> 2;
  int scho = (t & 3) * 8;
  const unsigned short* Ag = A + (size_t)(bm * 128 + srow) * DMODEL + scho;
  const unsigned short* Bg = Bt + (size_t)(bn * 128 + srow) * DMODEL + scho;

  // prologue: stage K-tile 0 into buf 0
  gl16(Ag, &As[0][t * 8]);
  gl16(Ag + 64 * DMODEL, &As[0][(t + 256) * 8]);
  gl16(Bg, &Bs[0][t * 8]);
  gl16(Bg + 64 * DMODEL, &Bs[0][(t + 256) * 8]);
  __syncthreads();

  for (int i = 0; i < 32; i++) {
    int cur = i & 1, nxt = cur ^ 1;
    if (i < 31) {          // issue next-tile staging; lands during this tile's MFMA
      int k1 = (i + 1) * 32;
      gl16(Ag + k1, &As[nxt][t * 8]);
      gl16(Ag + k1 + 64 * DMODEL, &As[nxt][(t + 256) * 8]);
      gl16(Bg + k1, &Bs[nxt][t * 8]);
      gl16(Bg + k1 + 64 * DMODEL, &Bs[nxt][(t + 256) * 8]);
    }
    bf16x8 af[4], bfr[4];
#pragma unroll
    for (int ii = 0; ii < 4; ii++)
      af[ii] = *(const bf16x8*)&As[cur][(wr * 64 + ii * 16 + lr) * 32 + lg * 8];
#pragma unroll
    for (int jj = 0; jj < 4; jj++)
      bfr[jj] = *(const bf16x8*)&Bs[cur][(wc * 64 + jj * 16 + lr) * 32 + lg * 8];
#pragma unroll
    for (int ii = 0; ii < 4; ii++)
#pragma unroll
      for (int jj = 0; jj < 4; jj++)
        acc[ii][jj] = __builtin_amdgcn_mfma_f32_16x16x32_bf16(af[ii], bfr[jj], acc[ii][jj], 0, 0, 0);
    __syncthreads();   // drains this iter's prefetch + guards buffer reuse
  }

  int nc0 = bn * 128 + wc * 64;
  int which = nc0 >> 10;
  int h = (nc0 & 1023) >> 6;
#pragma unroll
  for (int i = 0; i < 4; i++) {
#pragma unroll
    for (int r = 0; r < 4; r++) {
      int m = bm * 128 + wr * 64 + i * 16 + lg * 4 + r;
      int b = m >> 11;
      int n = m & (NTOK - 1);
      size_t obase = ((size_t)(b * NHEAD + h) * NTOK + n) * DHEAD;
      if (which == 2) {
#pragma unroll
        for (int j = 0; j < 4; j++) Vh[obase + j * 16 + lr] = f2b(acc[i][j][r]);
      } else {
        unsigned short* dst = which ? Kh : Qh;
        float qs = which ? 1.0f : QSCALE;   // fold attn scale * log2(e) into Q
#pragma unroll
        for (int j = 0; j < 2; j++) {
          int d = j * 16 + lr;
          float t1 = acc[i][j][r];
          float t2 = acc[i][j + 2][r];
          float c1 = cos_t[n * DHEAD + d],      s1 = sin_t[n * DHEAD + d];
          float c2 = cos_t[n * DHEAD + d + 32], s2 = sin_t[n * DHEAD + d + 32];
          dst[obase + d]      = f2b((t1 * c1 - t2 * s1) * qs);
          dst[obase + d + 32] = f2b((t2 * c2 + t1 * s2) * qs);
        }
      }
    }
  }
}

// ---------------- flash attention (causal), 1 q-tile (64 rows) per block ----------------
// Grid 32(bh) x 32(j). Balanced j->qt mapping. 40KB LDS -> 4 blocks/CU.
// Swapped QK^T + in-lane softmax (q-row = lr), defer-max, packed P writes,
// double-buffered K (global_load_lds) and V (reg, write-late).
__global__ __launch_bounds__(256, 4) void k_attn(
    const unsigned short* __restrict__ Qh, const unsigned short* __restrict__ Kh,
    const unsigned short* __restrict__ Vh, unsigned short* __restrict__ AO) {
  int bh = blockIdx.x;      // x-major: linear%8 = bh%8 -> same-head blocks share an XCD
  int j  = blockIdx.y;
  int m8 = j & 7, k8 = j >> 3;
  int qt = (k8 == 0) ? 31 - m8 : (k8 == 1) ? m8 : (k8 == 2) ? 23 - m8 : 8 + m8;
  int t = threadIdx.x;
  int l = t & 63, w = t >> 6;
  int lr = l & 15, lg = l >> 4;

  __shared__ unsigned short Ks[2][64 * 64];  // [kv][d], XOR-swizzled rows
  __shared__ unsigned short Vt[2][64 * 64];  // [d][kv], XOR-swizzled rows
  __shared__ unsigned short Ps[4][16 * 64];  // per-wave P[q][kv]

  const unsigned short* Qb = Qh + (size_t)bh * NTOK * DHEAD;
  const unsigned short* Kb = Kh + (size_t)bh * NTOK * DHEAD;
  const unsigned short* Vb = Vh + (size_t)bh * NTOK * DHEAD;

  int qrow = qt * 64 + w * 16 + lr;
  bf16x8 aq0 = *(const bf16x8*)&Qb[(size_t)qrow * DHEAD + lg * 8];
  bf16x8 aq1 = *(const bf16x8*)&Qb[(size_t)qrow * DHEAD + 32 + lg * 8];

  f32x4 accO[4] = {};
  float mrow = -1e38f;    // running max (log2 domain), q-row = lr
  float lsum = 0.f;

  int srow = t >> 3;           // K staging row 0..31 (+32 second)
  int spc  = t & 7;            // 16B chunk in 128B row
  int vr0  = (t >> 3) * 2;     // V staging row pair

  gl16(Kb + (size_t)srow * DHEAD + (spc ^ (srow & 7)) * 8, &Ks[0][t * 8]);
  gl16(Kb + (size_t)(srow + 32) * DHEAD + (spc ^ ((srow + 32) & 7)) * 8, &Ks[0][(t + 256) * 8]);
  {
    bf16x8 v0 = *(const bf16x8*)&Vb[(size_t)vr0 * DHEAD + spc * 8];
    bf16x8 v1 = *(const bf16x8*)&Vb[(size_t)(vr0 + 1) * DHEAD + spc * 8];
#pragma unroll
    for (int jj = 0; jj < 8; jj++) {
      int d = spc * 8 + jj;
      int sw = ((d & 7) ^ ((d >> 3) & 7)) << 4;
      unsigned pk = (unsigned)(unsigned short)v0[jj] | ((unsigned)(unsigned short)v1[jj] << 16);
      *(unsigned*)((char*)Vt[0] + d * 128 + ((vr0 * 2) ^ sw)) = pk;
    }
  }
  __syncthreads();

  for (int kt = 0; kt <= qt; ++kt) {
    int cur = kt & 1, nxt = cur ^ 1;
    int kv0 = kt * 64;
    bool notlast = (kt < qt);

    bf16x8 pv0, pv1;
    if (notlast) {
      int kvn = kv0 + 64;
      gl16(Kb + (size_t)(kvn + srow) * DHEAD + (spc ^ (srow & 7)) * 8, &Ks[nxt][t * 8]);
      gl16(Kb + (size_t)(kvn + srow + 32) * DHEAD + (spc ^ ((srow + 32) & 7)) * 8,
           &Ks[nxt][(t + 256) * 8]);
      pv0 = *(const bf16x8*)&Vb[(size_t)(kvn + vr0) * DHEAD + spc * 8];
      pv1 = *(const bf16x8*)&Vb[(size_t)(kvn + vr0 + 1) * DHEAD + spc * 8];
    }

    // ---- S^T = K Q^T : lane holds s[kv = nf*16+lg*4+r] for q-row (lr)
    f32x4 s[4];
#pragma unroll
    for (int nf = 0; nf < 4; nf++) {
      int krow = nf * 16 + lr;
      const char* kbase = (const char*)Ks[cur] + krow * 128;
      bf16x8 bk0 = *(const bf16x8*)(kbase + ((lg * 16) ^ ((krow & 7) << 4)));
      bf16x8 bk1 = *(const bf16x8*)(kbase + ((lg * 16 + 64) ^ ((krow & 7) << 4)));
      f32x4 z = {};
      z = __builtin_amdgcn_mfma_f32_16x16x32_bf16(bk0, aq0, z, 0, 0, 0);
      s[nf] = __builtin_amdgcn_mfma_f32_16x16x32_bf16(bk1, aq1, z, 0, 0, 0);
    }

    if (kt == qt) {
      int qr = qt * 64 + w * 16 + lr;
#pragma unroll
      for (int nf = 0; nf < 4; nf++)
#pragma unroll
        for (int r = 0; r < 4; r++)
          if (kv0 + nf * 16 + lg * 4 + r > qr) s[nf][r] = -1e30f;
    }

    // ---- online softmax
    float t1m = fmaxf(fmaxf(s[0][0], s[0][1]), s[0][2]);
    float t2m = fmaxf(fmaxf(s[0][3], s[1][0]), s[1][1]);
    float t3m = fmaxf(fmaxf(s[1][2], s[1][3]), s[2][0]);
    float t4m = fmaxf(fmaxf(s[2][1], s[2][2]), s[2][3]);
    float t5m = fmaxf(fmaxf(s[3][0], s[3][1]), s[3][2]);
    float pm = fmaxf(fmaxf(fmaxf(t1m, t2m), t3m), fmaxf(fmaxf(t4m, t5m), s[3][3]));
    pm = fmaxf(pm, __shfl_xor(pm, 16, 64));
    pm = fmaxf(pm, __shfl_xor(pm, 32, 64));
    if (__any(pm > mrow + 8.0f)) {   // defer-max
      float mnew = fmaxf(mrow, pm);
      float corr = exp2f(mrow - mnew);
      mrow = mnew;
      lsum *= corr;
      float c0 = __shfl(corr, lg * 4 + 0, 64);
      float c1 = __shfl(corr, lg * 4 + 1, 64);
      float c2 = __shfl(corr, lg * 4 + 2, 64);
      float c3 = __shfl(corr, lg * 4 + 3, 64);
#pragma unroll
      for (int df = 0; df < 4; df++) {
        accO[df][0] *= c0; accO[df][1] *= c1;
        accO[df][2] *= c2; accO[df][3] *= c3;
      }
    }
    {
      float m = mrow;
      float sum = 0.f;
      char* pw = (char*)Ps[w] + lr * 128;
      int sw = (lr & 7) << 4;
#pragma unroll
      for (int nf = 0; nf < 4; nf++) {
        float p0 = exp2f(s[nf][0] - m);
        float p1 = exp2f(s[nf][1] - m);
        float p2 = exp2f(s[nf][2] - m);
        float p3 = exp2f(s[nf][3] - m);
        sum += (p0 + p1) + (p2 + p3);
        unsigned w0 = pk2bf(p0, p1);
        unsigned w1 = pk2bf(p2, p3);
        *(uint64_t*)(pw + ((nf * 32 + lg * 8) ^ sw)) = (uint64_t)w0 | ((uint64_t)w1 << 32);
      }
      sum += __shfl_xor(sum, 16, 64);
      sum += __shfl_xor(sum, 32, 64);
      lsum += sum;
    }

    // ---- O += P V
#pragma unroll
    for (int ks = 0; ks < 2; ks++) {
      const char* pb = (const char*)Ps[w] + lr * 128;
      bf16x8 ap = *(const bf16x8*)(pb + ((lg * 16 + ks * 64) ^ ((lr & 7) << 4)));
#pragma unroll
      for (int df = 0; df < 4; df++) {
        int col = df * 16 + lr;
        int sw = ((col & 7) ^ ((col >> 3) & 7)) << 4;
        bf16x8 bv = *(const bf16x8*)((const char*)Vt[cur] + col * 128 + ((lg * 16 + ks * 64) ^ sw));
        accO[df] = __builtin_amdgcn_mfma_f32_16x16x32_bf16(ap, bv, accO[df], 0, 0, 0);
      }
    }

    if (notlast) {
#pragma unroll
      for (int jj = 0; jj < 8; jj++) {
        int d = spc * 8 + jj;
        int sw = ((d & 7) ^ ((d >> 3) & 7)) << 4;
        unsigned pk = (unsigned)(unsigned short)pv0[jj] | ((unsigned)(unsigned short)pv1[jj] << 16);
        *(unsigned*)((char*)Vt[nxt] + d * 128 + ((vr0 * 2) ^ sw)) = pk;
      }
    }
    __syncthreads();
  }

  int b = bh >> 4, h = bh & 15;
  float li = 1.0f / lsum;
  float l0 = __shfl(li, lg * 4 + 0, 64);
  float l1 = __shfl(li, lg * 4 + 1, 64);
  float l2 = __shfl(li, lg * 4 + 2, 64);
  float l3 = __shfl(li, lg * 4 + 3, 64);
  int qbase = qt * 64 + w * 16;
#pragma unroll
  for (int df = 0; df < 4; df++) {
    int d = df * 16 + lr;
    size_t ob = ((size_t)(b * NTOK + qbase + lg * 4)) * DMODEL + h * DHEAD + d;
    AO[ob + 0 * DMODEL] = f2b(accO[df][0] * l0);
    AO[ob + 1 * DMODEL] = f2b(accO[df][1] * l1);
    AO[ob + 2 * DMODEL] = f2b(accO[df][2] * l2);
    AO[ob + 3 * DMODEL] = f2b(accO[df][3] * l3);
  }
}

// ---- out GEMM: AO bf16 [4096][1024] @ w_o^T + bias -> fp32, BM=128 BN=64, 2-phase ----
__global__ __launch_bounds__(256) void k_out_gemm(
    const unsigned short* __restrict__ A, const unsigned short* __restrict__ Bt,
    const float* __restrict__ bias, float* __restrict__ out) {
  __shared__ unsigned short As[2][128 * 32];
  __shared__ unsigned short Bs[2][64 * 32];
  int bm = blockIdx.x, bn = blockIdx.y;
  int t = threadIdx.x;
  int l = t & 63, w = t >> 6;
  int wr = w >> 1, wc = w & 1;          // wave: 64 rows x 32 cols
  int lr = l & 15, lg = l >> 4;
  f32x4 acc[4][2] = {};

  int srow = t >> 2;
  int scho = (t & 3) * 8;
  const unsigned short* Ag = A + (size_t)(bm * 128 + srow) * DMODEL + scho;
  const unsigned short* Bg = Bt + (size_t)(bn * 64 + srow) * DMODEL + scho;  // srow<64 used

  // prologue: stage K-tile 0
  gl16(Ag, &As[0][t * 8]);
  gl16(Ag + 64 * DMODEL, &As[0][(t + 256) * 8]);
  if (srow < 64) gl16(Bg, &Bs[0][t * 8]);
  __syncthreads();

  for (int i = 0; i < 32; i++) {
    int cur = i & 1, nxt = cur ^ 1;
    if (i < 31) {
      int k1 = (i + 1) * 32;
      gl16(Ag + k1, &As[nxt][t * 8]);
      gl16(Ag + k1 + 64 * DMODEL, &As[nxt][(t + 256) * 8]);
      if (srow < 64) gl16(Bg + k1, &Bs[nxt][t * 8]);
    }
    bf16x8 af[4], bfr[2];
#pragma unroll
    for (int ii = 0; ii < 4; ii++)
      af[ii] = *(const bf16x8*)&As[cur][(wr * 64 + ii * 16 + lr) * 32 + lg * 8];
#pragma unroll
    for (int jj = 0; jj < 2; jj++)
      bfr[jj] = *(const bf16x8*)&Bs[cur][(wc * 32 + jj * 16 + lr) * 32 + lg * 8];
#pragma unroll
    for (int ii = 0; ii < 4; ii++)
#pragma unroll
      for (int jj = 0; jj < 2; jj++)
        acc[ii][jj] = __builtin_amdgcn_mfma_f32_16x16x32_bf16(af[ii], bfr[jj], acc[ii][jj], 0, 0, 0);
    __syncthreads();
  }
  int nc0 = bn * 64 + wc * 32;
#pragma unroll
  for (int i = 0; i < 4; i++)
#pragma unroll
    for (int r = 0; r < 4; r++) {
      int m = bm * 128 + wr * 64 + i * 16 + lg * 4 + r;
      float* orow = out + (size_t)m * DMODEL;
#pragma unroll
      for (int j = 0; j < 2; j++) {
        int col = nc0 + j * 16 + lr;
        orow[col] = acc[i][j][r] + bias[col];
      }
    }
}

extern "C" void kernel_launch(void* const* d_in, const int* in_sizes, int n_in,
                              void* d_out, int out_size, void* d_ws, size_t ws_size,
                              hipStream_t stream) {
  const float* x      = (const float*)d_in[0];
  const float* norm_w = (const float*)d_in[1];
  const float* w_qkv  = (const float*)d_in[2];
  const float* w_o    = (const float*)d_in[3];
  const float* b_o    = (const float*)d_in[4];
  const float* sin_t  = (const float*)d_in[5];
  const float* cos_t  = (const float*)d_in[6];
  float* out = (float*)d_out;

  char* ws = (char*)d_ws;
  unsigned short* xn    = (unsigned short*)(ws + (0u << 20));   // 8 MB
  unsigned short* wqkvT = (unsigned short*)(ws + (8u << 20));   // 6 MB
  unsigned short* woT   = (unsigned short*)(ws + (14u << 20));  // 2 MB
  unsigned short* Qh    = (unsigned short*)(ws + (16u << 20));  // 8 MB  [b][h][n][d]
  unsigned short* Kh    = (unsigned short*)(ws + (24u << 20));  // 8 MB
  unsigned short* Vh    = (unsigned short*)(ws + (32u << 20));  // 8 MB
  unsigned short* AO    = (unsigned short*)(ws + (40u << 20));  // 8 MB  [b][n][h*d]

  hipLaunchKernelGGL(k_rmsnorm, dim3(NROWS), dim3(256), 0, stream, x, norm_w, xn);
  hipLaunchKernelGGL(k_transpose_bf16, dim3(16, 48), dim3(256), 0, stream, w_qkv, wqkvT, DMODEL, NQKV);
  hipLaunchKernelGGL(k_transpose_bf16, dim3(16, 16), dim3(256), 0, stream, w_o, woT, DMODEL, DMODEL);
  hipLaunchKernelGGL(k_qkv_gemm, dim3(32, 24), dim3(256), 0, stream, xn, wqkvT, sin_t, cos_t, Qh, Kh, Vh);
  hipLaunchKernelGGL(k_attn, dim3(32, 32), dim3(256), 0, stream, Qh, Kh, Vh, AO);
  hipLaunchKernelGGL(k_out_gemm, dim3(32, 16), dim3(256), 0, stream, AO, woT, b_o, out);
}

// Round 7
// 120.010 us; speedup vs baseline: 1.9193x; 1.0037x over previous
//
#include <hip/hip_runtime.h>
#include <hip/hip_bf16.h>
#include <stdint.h>
#include <stddef.h>

#define NTOK   2048
#define NHEAD  16
#define DHEAD  64
#define DMODEL 1024
#define NROWS  4096      // B * NTOK
#define NQKV   3072
#define RMS_EPS 1.1920928955078125e-07f
// attention scale 1/8 with log2(e) folded in (scores in log2 domain)
#define QSCALE 0.1803368801111204f

typedef short bf16x8 __attribute__((ext_vector_type(8)));
typedef float f32x4  __attribute__((ext_vector_type(4)));
typedef unsigned short u16x4 __attribute__((ext_vector_type(4)));
typedef unsigned short u16x8 __attribute__((ext_vector_type(8)));

__device__ __forceinline__ unsigned short f2b(float f) {
  unsigned u = __builtin_bit_cast(unsigned, f);
  return (unsigned short)((u + 0x7fffu + ((u >> 16) & 1u)) >> 16);  // RNE
}

// packed f32x2 -> bf16x2
__device__ __forceinline__ unsigned pk2bf(float a, float b) {
  __hip_bfloat162 h = __float22bfloat162_rn(make_float2(a, b));
  unsigned u;
  __builtin_memcpy(&u, &h, 4);
  return u;
}

__device__ __forceinline__ void gl16(const void* g, void* l) {
  __builtin_amdgcn_global_load_lds((__attribute__((address_space(1))) void*)g,
                                   (__attribute__((address_space(3))) void*)l,
                                   16, 0, 0);
}

// ---------------- RMSNorm: x fp32 [4096][1024] -> xn bf16 ----------------
__global__ __launch_bounds__(256) void k_rmsnorm(const float* __restrict__ x,
                                                 const float* __restrict__ w,
                                                 unsigned short* __restrict__ xn) {
  int row = blockIdx.x;
  int t = threadIdx.x;
  float4 v = ((const float4*)(x + (size_t)row * DMODEL))[t];
  float ss = v.x * v.x + v.y * v.y + v.z * v.z + v.w * v.w;
#pragma unroll
  for (int m = 1; m < 64; m <<= 1) ss += __shfl_xor(ss, m, 64);
  __shared__ float red[4];
  if ((t & 63) == 0) red[t >> 6] = ss;
  __syncthreads();
  float tot = (red[0] + red[1]) + (red[2] + red[3]);
  float rs = rsqrtf(tot * (1.0f / DMODEL) + RMS_EPS);
  float4 wv = ((const float4*)w)[t];
  u16x4 o;
  o.x = f2b(v.x * rs * wv.x);
  o.y = f2b(v.y * rs * wv.y);
  o.z = f2b(v.z * rs * wv.z);
  o.w = f2b(v.w * rs * wv.w);
  *(u16x4*)(xn + (size_t)row * DMODEL + t * 4) = o;
}

// ------------- transpose+convert: W fp32 [K][Nw] -> Wt bf16 [Nw][K] -------------
__global__ __launch_bounds__(256) void k_transpose_bf16(const float* __restrict__ W,
                                                        unsigned short* __restrict__ Wt,
                                                        int K, int Nw) {
  __shared__ float tile[64][65];
  int bk = blockIdx.x * 64;
  int bn = blockIdx.y * 64;
  int t = threadIdx.x;
  int tr = t >> 4;
  int tc = (t & 15) * 4;
#pragma unroll
  for (int rr = 0; rr < 64; rr += 16) {
    float4 v = *(const float4*)&W[(size_t)(bk + tr + rr) * Nw + bn + tc];
    tile[tr + rr][tc + 0] = v.x;
    tile[tr + rr][tc + 1] = v.y;
    tile[tr + rr][tc + 2] = v.z;
    tile[tr + rr][tc + 3] = v.w;
  }
  __syncthreads();
#pragma unroll
  for (int rr = 0; rr < 64; rr += 16) {
    int n = bn + tr + rr;
    u16x4 o;
    o.x = f2b(tile[tc + 0][tr + rr]);
    o.y = f2b(tile[tc + 1][tr + rr]);
    o.z = f2b(tile[tc + 2][tr + rr]);
    o.w = f2b(tile[tc + 3][tr + rr]);
    *(u16x4*)&Wt[(size_t)n * K + bk + tc] = o;
  }
}

// ------- QKV GEMM (128x128, BK=32, T3 2-phase double-buffered) + fused RoPE -------
__global__ __launch_bounds__(256) void k_qkv_gemm(
    const unsigned short* __restrict__ A, const unsigned short* __restrict__ Bt,
    const float* __restrict__ sin_t, const float* __restrict__ cos_t,
    unsigned short* __restrict__ Qh, unsigned short* __restrict__ Kh,
    unsigned short* __restrict__ Vh) {
  __shared__ unsigned short As[2][128 * 32];
  __shared__ unsigned short Bs[2][128 * 32];
  int bm = blockIdx.x, bn = blockIdx.y;
  int t = threadIdx.x;
  int l = t & 63, w = t >> 6;
  int wr = w >> 1, wc = w & 1;
  int lr = l & 15, lg = l >> 4;
  f32x4 acc[4][4] = {};

  int srow = t >> 2;
  int scho = (t & 3) * 8;
  const unsigned short* Ag = A + (size_t)(bm * 128 + srow) * DMODEL + scho;
  const unsigned short* Bg = Bt + (size_t)(bn * 128 + srow) * DMODEL + scho;

  gl16(Ag, &As[0][t * 8]);
  gl16(Ag + 64 * DMODEL, &As[0][(t + 256) * 8]);
  gl16(Bg, &Bs[0][t * 8]);
  gl16(Bg + 64 * DMODEL, &Bs[0][(t + 256) * 8]);
  __syncthreads();

  for (int i = 0; i < 32; i++) {
    int cur = i & 1, nxt = cur ^ 1;
    if (i < 31) {
      int k1 = (i + 1) * 32;
      gl16(Ag + k1, &As[nxt][t * 8]);
      gl16(Ag + k1 + 64 * DMODEL, &As[nxt][(t + 256) * 8]);
      gl16(Bg + k1, &Bs[nxt][t * 8]);
      gl16(Bg + k1 + 64 * DMODEL, &Bs[nxt][(t + 256) * 8]);
    }
    bf16x8 af[4], bfr[4];
#pragma unroll
    for (int ii = 0; ii < 4; ii++)
      af[ii] = *(const bf16x8*)&As[cur][(wr * 64 + ii * 16 + lr) * 32 + lg * 8];
#pragma unroll
    for (int jj = 0; jj < 4; jj++)
      bfr[jj] = *(const bf16x8*)&Bs[cur][(wc * 64 + jj * 16 + lr) * 32 + lg * 8];
#pragma unroll
    for (int ii = 0; ii < 4; ii++)
#pragma unroll
      for (int jj = 0; jj < 4; jj++)
        acc[ii][jj] = __builtin_amdgcn_mfma_f32_16x16x32_bf16(af[ii], bfr[jj], acc[ii][jj], 0, 0, 0);
    __syncthreads();
  }

  int nc0 = bn * 128 + wc * 64;
  int which = nc0 >> 10;
  int h = (nc0 & 1023) >> 6;
#pragma unroll
  for (int i = 0; i < 4; i++) {
#pragma unroll
    for (int r = 0; r < 4; r++) {
      int m = bm * 128 + wr * 64 + i * 16 + lg * 4 + r;
      int b = m >> 11;
      int n = m & (NTOK - 1);
      size_t obase = ((size_t)(b * NHEAD + h) * NTOK + n) * DHEAD;
      if (which == 2) {
#pragma unroll
        for (int j = 0; j < 4; j++) Vh[obase + j * 16 + lr] = f2b(acc[i][j][r]);
      } else {
        unsigned short* dst = which ? Kh : Qh;
        float qs = which ? 1.0f : QSCALE;
#pragma unroll
        for (int j = 0; j < 2; j++) {
          int d = j * 16 + lr;
          float t1 = acc[i][j][r];
          float t2 = acc[i][j + 2][r];
          float c1 = cos_t[n * DHEAD + d],      s1 = sin_t[n * DHEAD + d];
          float c2 = cos_t[n * DHEAD + d + 32], s2 = sin_t[n * DHEAD + d + 32];
          dst[obase + d]      = f2b((t1 * c1 - t2 * s1) * qs);
          dst[obase + d + 32] = f2b((t2 * c2 + t1 * s2) * qs);
        }
      }
    }
  }
}

// ---- flash attention (causal) with kv-split: 48 work items per bh, sorted desc ----
// slot -> (qt, kt0, kt1); qt<16 = full block (writes AO); qt>=16 = half block
// (writes unnormalized bf16 O partial + f32 m/l; merged by k_merge).
#define SL(q, a, b) ((q) | ((a) << 6) | ((b) << 12))
__constant__ int SLOTS[48] = {
  SL(31,0,16), SL(31,16,32), SL(30,15,31), SL(15,0,16),
  SL(30,0,15), SL(29,0,15),  SL(29,15,30), SL(28,14,29), SL(14,0,15),
  SL(28,0,14), SL(27,0,14),  SL(27,14,28), SL(26,13,27), SL(13,0,14),
  SL(26,0,13), SL(25,0,13),  SL(25,13,26), SL(24,12,25), SL(12,0,13),
  SL(24,0,12), SL(23,0,12),  SL(23,12,24), SL(22,11,23), SL(11,0,12),
  SL(22,0,11), SL(21,0,11),  SL(21,11,22), SL(20,10,21), SL(10,0,11),
  SL(20,0,10), SL(19,0,10),  SL(19,10,20), SL(18,9,19),  SL(9,0,10),
  SL(18,0,9),  SL(17,0,9),   SL(17,9,18),  SL(16,8,17),  SL(8,0,9),
  SL(16,0,8),  SL(7,0,8),    SL(6,0,7),    SL(5,0,6),    SL(4,0,5),
  SL(3,0,4),   SL(2,0,3),    SL(1,0,2),    SL(0,0,1)
};

__global__ __launch_bounds__(256, 4) void k_attn(
    const unsigned short* __restrict__ Qh, const unsigned short* __restrict__ Kh,
    const unsigned short* __restrict__ Vh, unsigned short* __restrict__ AO,
    unsigned short* __restrict__ Opart, float* __restrict__ Mpart,
    float* __restrict__ Lpart) {
  int bh = blockIdx.x;      // x-major: linear%8 = bh%8 -> same-head blocks share an XCD
  int sv = SLOTS[blockIdx.y];
  int qt = sv & 63, kt0 = (sv >> 6) & 63, kt1 = sv >> 12;
  bool partial = (kt0 != 0) || (kt1 != qt + 1);
  int half = (kt0 != 0) ? 1 : 0;
  int t = threadIdx.x;
  int l = t & 63, w = t >> 6;
  int lr = l & 15, lg = l >> 4;

  __shared__ unsigned short Ks[2][64 * 64];  // [kv][d], XOR-swizzled rows
  __shared__ unsigned short Vt[2][64 * 64];  // [d][kv], XOR-swizzled rows
  __shared__ unsigned short Ps[4][16 * 64];  // per-wave P[q][kv]

  const unsigned short* Qb = Qh + (size_t)bh * NTOK * DHEAD;
  const unsigned short* Kb = Kh + (size_t)bh * NTOK * DHEAD;
  const unsigned short* Vb = Vh + (size_t)bh * NTOK * DHEAD;

  int qrow = qt * 64 + w * 16 + lr;
  bf16x8 aq0 = *(const bf16x8*)&Qb[(size_t)qrow * DHEAD + lg * 8];
  bf16x8 aq1 = *(const bf16x8*)&Qb[(size_t)qrow * DHEAD + 32 + lg * 8];

  f32x4 accO[4] = {};
  float mrow = -1e38f;    // running max (log2 domain), q-row = lr
  float lsum = 0.f;

  int srow = t >> 3;
  int spc  = t & 7;
  int vr0  = (t >> 3) * 2;

  {
    int kv0 = kt0 * 64;
    gl16(Kb + (size_t)(kv0 + srow) * DHEAD + (spc ^ (srow & 7)) * 8, &Ks[0][t * 8]);
    gl16(Kb + (size_t)(kv0 + srow + 32) * DHEAD + (spc ^ ((srow + 32) & 7)) * 8,
         &Ks[0][(t + 256) * 8]);
    bf16x8 v0 = *(const bf16x8*)&Vb[(size_t)(kv0 + vr0) * DHEAD + spc * 8];
    bf16x8 v1 = *(const bf16x8*)&Vb[(size_t)(kv0 + vr0 + 1) * DHEAD + spc * 8];
#pragma unroll
    for (int jj = 0; jj < 8; jj++) {
      int d = spc * 8 + jj;
      int sw = ((d & 7) ^ ((d >> 3) & 7)) << 4;
      unsigned pk = (unsigned)(unsigned short)v0[jj] | ((unsigned)(unsigned short)v1[jj] << 16);
      *(unsigned*)((char*)Vt[0] + d * 128 + ((vr0 * 2) ^ sw)) = pk;
    }
  }
  __syncthreads();

  for (int kt = kt0; kt < kt1; ++kt) {
    int cur = (kt - kt0) & 1, nxt = cur ^ 1;
    int kv0 = kt * 64;
    bool notlast = (kt + 1 < kt1);

    bf16x8 pv0, pv1;
    if (notlast) {
      int kvn = kv0 + 64;
      gl16(Kb + (size_t)(kvn + srow) * DHEAD + (spc ^ (srow & 7)) * 8, &Ks[nxt][t * 8]);
      gl16(Kb + (size_t)(kvn + srow + 32) * DHEAD + (spc ^ ((srow + 32) & 7)) * 8,
           &Ks[nxt][(t + 256) * 8]);
      pv0 = *(const bf16x8*)&Vb[(size_t)(kvn + vr0) * DHEAD + spc * 8];
      pv1 = *(const bf16x8*)&Vb[(size_t)(kvn + vr0 + 1) * DHEAD + spc * 8];
    }

    // ---- S^T = K Q^T : lane holds s[kv = nf*16+lg*4+r] for q-row (lr)
    f32x4 s[4];
#pragma unroll
    for (int nf = 0; nf < 4; nf++) {
      int krow = nf * 16 + lr;
      const char* kbase = (const char*)Ks[cur] + krow * 128;
      bf16x8 bk0 = *(const bf16x8*)(kbase + ((lg * 16) ^ ((krow & 7) << 4)));
      bf16x8 bk1 = *(const bf16x8*)(kbase + ((lg * 16 + 64) ^ ((krow & 7) << 4)));
      f32x4 z = {};
      z = __builtin_amdgcn_mfma_f32_16x16x32_bf16(bk0, aq0, z, 0, 0, 0);
      s[nf] = __builtin_amdgcn_mfma_f32_16x16x32_bf16(bk1, aq1, z, 0, 0, 0);
    }

    if (kt == qt) {
      int qr = qt * 64 + w * 16 + lr;
#pragma unroll
      for (int nf = 0; nf < 4; nf++)
#pragma unroll
        for (int r = 0; r < 4; r++)
          if (kv0 + nf * 16 + lg * 4 + r > qr) s[nf][r] = -1e30f;
    }

    // ---- online softmax (in-lane + 2 shfl), defer-max
    float t1m = fmaxf(fmaxf(s[0][0], s[0][1]), s[0][2]);
    float t2m = fmaxf(fmaxf(s[0][3], s[1][0]), s[1][1]);
    float t3m = fmaxf(fmaxf(s[1][2], s[1][3]), s[2][0]);
    float t4m = fmaxf(fmaxf(s[2][1], s[2][2]), s[2][3]);
    float t5m = fmaxf(fmaxf(s[3][0], s[3][1]), s[3][2]);
    float pm = fmaxf(fmaxf(fmaxf(t1m, t2m), t3m), fmaxf(fmaxf(t4m, t5m), s[3][3]));
    pm = fmaxf(pm, __shfl_xor(pm, 16, 64));
    pm = fmaxf(pm, __shfl_xor(pm, 32, 64));
    if (__any(pm > mrow + 8.0f)) {
      float mnew = fmaxf(mrow, pm);
      float corr = exp2f(mrow - mnew);
      mrow = mnew;
      lsum *= corr;
      float c0 = __shfl(corr, lg * 4 + 0, 64);
      float c1 = __shfl(corr, lg * 4 + 1, 64);
      float c2 = __shfl(corr, lg * 4 + 2, 64);
      float c3 = __shfl(corr, lg * 4 + 3, 64);
#pragma unroll
      for (int df = 0; df < 4; df++) {
        accO[df][0] *= c0; accO[df][1] *= c1;
        accO[df][2] *= c2; accO[df][3] *= c3;
      }
    }
    {
      float m = mrow;
      float sum = 0.f;
      char* pw = (char*)Ps[w] + lr * 128;
      int sw = (lr & 7) << 4;
#pragma unroll
      for (int nf = 0; nf < 4; nf++) {
        float p0 = exp2f(s[nf][0] - m);
        float p1 = exp2f(s[nf][1] - m);
        float p2 = exp2f(s[nf][2] - m);
        float p3 = exp2f(s[nf][3] - m);
        sum += (p0 + p1) + (p2 + p3);
        unsigned w0 = pk2bf(p0, p1);
        unsigned w1 = pk2bf(p2, p3);
        *(uint64_t*)(pw + ((nf * 32 + lg * 8) ^ sw)) = (uint64_t)w0 | ((uint64_t)w1 << 32);
      }
      sum += __shfl_xor(sum, 16, 64);
      sum += __shfl_xor(sum, 32, 64);
      lsum += sum;
    }

    // ---- O += P V
#pragma unroll
    for (int ks = 0; ks < 2; ks++) {
      const char* pb = (const char*)Ps[w] + lr * 128;
      bf16x8 ap = *(const bf16x8*)(pb + ((lg * 16 + ks * 64) ^ ((lr & 7) << 4)));
#pragma unroll
      for (int df = 0; df < 4; df++) {
        int col = df * 16 + lr;
        int sw = ((col & 7) ^ ((col >> 3) & 7)) << 4;
        bf16x8 bv = *(const bf16x8*)((const char*)Vt[cur] + col * 128 + ((lg * 16 + ks * 64) ^ sw));
        accO[df] = __builtin_amdgcn_mfma_f32_16x16x32_bf16(ap, bv, accO[df], 0, 0, 0);
      }
    }

    if (notlast) {
#pragma unroll
      for (int jj = 0; jj < 8; jj++) {
        int d = spc * 8 + jj;
        int sw = ((d & 7) ^ ((d >> 3) & 7)) << 4;
        unsigned pk = (unsigned)(unsigned short)pv0[jj] | ((unsigned)(unsigned short)pv1[jj] << 16);
        *(unsigned*)((char*)Vt[nxt] + d * 128 + ((vr0 * 2) ^ sw)) = pk;
      }
    }
    __syncthreads();
  }

  if (partial) {
    // ---- write unnormalized partial (bf16 O, f32 stats)
    int pbase = (((bh << 4) + (qt - 16)) << 1) + half;
    if (lg == 0) {
      Mpart[pbase * 64 + w * 16 + lr] = mrow;
      Lpart[pbase * 64 + w * 16 + lr] = lsum;
    }
    unsigned short* Od = Opart + (size_t)pbase * 4096;
#pragma unroll
    for (int df = 0; df < 4; df++)
#pragma unroll
      for (int r = 0; r < 4; r++)
        Od[(w * 16 + lg * 4 + r) * 64 + df * 16 + lr] = f2b(accO[df][r]);
  } else {
    int b = bh >> 4, h = bh & 15;
    float li = 1.0f / lsum;
    float l0 = __shfl(li, lg * 4 + 0, 64);
    float l1 = __shfl(li, lg * 4 + 1, 64);
    float l2 = __shfl(li, lg * 4 + 2, 64);
    float l3 = __shfl(li, lg * 4 + 3, 64);
    int qbase = qt * 64 + w * 16;
#pragma unroll
    for (int df = 0; df < 4; df++) {
      int d = df * 16 + lr;
      size_t ob = ((size_t)(b * NTOK + qbase + lg * 4)) * DMODEL + h * DHEAD + d;
      AO[ob + 0 * DMODEL] = f2b(accO[df][0] * l0);
      AO[ob + 1 * DMODEL] = f2b(accO[df][1] * l1);
      AO[ob + 2 * DMODEL] = f2b(accO[df][2] * l2);
      AO[ob + 3 * DMODEL] = f2b(accO[df][3] * l3);
    }
  }
}

// ---- merge two kv-halves for qt>=16: out = (O1*2^(m1-m) + O2*2^(m2-m)) / l ----
__global__ __launch_bounds__(256) void k_merge(const unsigned short* __restrict__ Opart,
                                               const float* __restrict__ Mpart,
                                               const float* __restrict__ Lpart,
                                               unsigned short* __restrict__ AO) {
  int bh = blockIdx.x, qq = blockIdx.y;
  int t = threadIdx.x;
  int row = t >> 2, d0 = (t & 3) << 4;
  int p0 = ((bh << 4) + qq) << 1;
  float m1 = Mpart[p0 * 64 + row],       l1 = Lpart[p0 * 64 + row];
  float m2 = Mpart[(p0 + 1) * 64 + row], l2 = Lpart[(p0 + 1) * 64 + row];
  float mm = fmaxf(m1, m2);
  float s1 = exp2f(m1 - mm), s2 = exp2f(m2 - mm);
  float li = 1.0f / (l1 * s1 + l2 * s2);
  float a1 = s1 * li, a2 = s2 * li;
  const unsigned short* O1 = Opart + (size_t)p0 * 4096 + row * 64 + d0;
  const unsigned short* O2 = O1 + 4096;
  int qt = 16 + qq;
  int b = bh >> 4, h = bh & 15;
  unsigned short* dst = AO + ((size_t)(b * NTOK + qt * 64 + row)) * DMODEL + h * DHEAD + d0;
#pragma unroll
  for (int c = 0; c < 2; c++) {
    u16x8 v1 = *(const u16x8*)(O1 + c * 8);
    u16x8 v2 = *(const u16x8*)(O2 + c * 8);
    u16x8 o;
#pragma unroll
    for (int e = 0; e < 8; e++) {
      float f1 = __builtin_bit_cast(float, (unsigned)v1[e] << 16);
      float g1 = __builtin_bit_cast(float, (unsigned)v2[e] << 16);
      o[e] = f2b(f1 * a1 + g1 * a2);
    }
    *(u16x8*)(dst + c * 8) = o;
  }
}

// ---- out GEMM: AO bf16 [4096][1024] @ w_o^T + bias -> fp32, BM=128 BN=64, 2-phase ----
__global__ __launch_bounds__(256) void k_out_gemm(
    const unsigned short* __restrict__ A, const unsigned short* __restrict__ Bt,
    const float* __restrict__ bias, float* __restrict__ out) {
  __shared__ unsigned short As[2][128 * 32];
  __shared__ unsigned short Bs[2][64 * 32];
  int bm = blockIdx.x, bn = blockIdx.y;
  int t = threadIdx.x;
  int l = t & 63, w = t >> 6;
  int wr = w >> 1, wc = w & 1;
  int lr = l & 15, lg = l >> 4;
  f32x4 acc[4][2] = {};

  int srow = t >> 2;
  int scho = (t & 3) * 8;
  const unsigned short* Ag = A + (size_t)(bm * 128 + srow) * DMODEL + scho;
  const unsigned short* Bg = Bt + (size_t)(bn * 64 + srow) * DMODEL + scho;

  gl16(Ag, &As[0][t * 8]);
  gl16(Ag + 64 * DMODEL, &As[0][(t + 256) * 8]);
  if (srow < 64) gl16(Bg, &Bs[0][t * 8]);
  __syncthreads();

  for (int i = 0; i < 32; i++) {
    int cur = i & 1, nxt = cur ^ 1;
    if (i < 31) {
      int k1 = (i + 1) * 32;
      gl16(Ag + k1, &As[nxt][t * 8]);
      gl16(Ag + k1 + 64 * DMODEL, &As[nxt][(t + 256) * 8]);
      if (srow < 64) gl16(Bg + k1, &Bs[nxt][t * 8]);
    }
    bf16x8 af[4], bfr[2];
#pragma unroll
    for (int ii = 0; ii < 4; ii++)
      af[ii] = *(const bf16x8*)&As[cur][(wr * 64 + ii * 16 + lr) * 32 + lg * 8];
#pragma unroll
    for (int jj = 0; jj < 2; jj++)
      bfr[jj] = *(const bf16x8*)&Bs[cur][(wc * 32 + jj * 16 + lr) * 32 + lg * 8];
#pragma unroll
    for (int ii = 0; ii < 4; ii++)
#pragma unroll
      for (int jj = 0; jj < 2; jj++)
        acc[ii][jj] = __builtin_amdgcn_mfma_f32_16x16x32_bf16(af[ii], bfr[jj], acc[ii][jj], 0, 0, 0);
    __syncthreads();
  }
  int nc0 = bn * 64 + wc * 32;
#pragma unroll
  for (int i = 0; i < 4; i++)
#pragma unroll
    for (int r = 0; r < 4; r++) {
      int m = bm * 128 + wr * 64 + i * 16 + lg * 4 + r;
      float* orow = out + (size_t)m * DMODEL;
#pragma unroll
      for (int j = 0; j < 2; j++) {
        int col = nc0 + j * 16 + lr;
        orow[col] = acc[i][j][r] + bias[col];
      }
    }
}

extern "C" void kernel_launch(void* const* d_in, const int* in_sizes, int n_in,
                              void* d_out, int out_size, void* d_ws, size_t ws_size,
                              hipStream_t stream) {
  const float* x      = (const float*)d_in[0];
  const float* norm_w = (const float*)d_in[1];
  const float* w_qkv  = (const float*)d_in[2];
  const float* w_o    = (const float*)d_in[3];
  const float* b_o    = (const float*)d_in[4];
  const float* sin_t  = (const float*)d_in[5];
  const float* cos_t  = (const float*)d_in[6];
  float* out = (float*)d_out;

  char* ws = (char*)d_ws;
  unsigned short* xn    = (unsigned short*)(ws + (0u << 20));   // 8 MB  (dead after qkv)
  unsigned short* wqkvT = (unsigned short*)(ws + (8u << 20));   // 6 MB  (dead after qkv)
  unsigned short* woT   = (unsigned short*)(ws + (14u << 20));  // 2 MB
  unsigned short* Qh    = (unsigned short*)(ws + (16u << 20));  // 8 MB  [b][h][n][d]
  unsigned short* Kh    = (unsigned short*)(ws + (24u << 20));  // 8 MB
  unsigned short* Vh    = (unsigned short*)(ws + (32u << 20));  // 8 MB
  unsigned short* AO    = (unsigned short*)(ws + (40u << 20));  // 8 MB  [b][n][h*d]
  // attn partials reuse regions dead during k_attn (rewritten every call):
  unsigned short* Opart = (unsigned short*)(ws + (0u << 20));           // 8 MB in xn
  float*          Mpart = (float*)(ws + (8u << 20));                    // 256 KB in wqkvT
  float*          Lpart = (float*)(ws + (8u << 20) + (1u << 18));       // 256 KB in wqkvT

  hipLaunchKernelGGL(k_rmsnorm, dim3(NROWS), dim3(256), 0, stream, x, norm_w, xn);
  hipLaunchKernelGGL(k_transpose_bf16, dim3(16, 48), dim3(256), 0, stream, w_qkv, wqkvT, DMODEL, NQKV);
  hipLaunchKernelGGL(k_transpose_bf16, dim3(16, 16), dim3(256), 0, stream, w_o, woT, DMODEL, DMODEL);
  hipLaunchKernelGGL(k_qkv_gemm, dim3(32, 24), dim3(256), 0, stream, xn, wqkvT, sin_t, cos_t, Qh, Kh, Vh);
  hipLaunchKernelGGL(k_attn, dim3(32, 48), dim3(256), 0, stream, Qh, Kh, Vh, AO, Opart, Mpart, Lpart);
  hipLaunchKernelGGL(k_merge, dim3(32, 16), dim3(256), 0, stream, Opart, Mpart, Lpart, AO);
  hipLaunchKernelGGL(k_out_gemm, dim3(32, 16), dim3(256), 0, stream, AO, woT, b_o, out);
}